// Round 2
// baseline (3328.062 us; speedup 1.0000x reference)
//
#include <hip/hip_runtime.h>
#include <math.h>

// FEDformer encoder layer, MI355X fp32 baseline.
// B=16, L=2048, D=512, H=8, E=64, M=64, DFF=2048, kernels (13,25).
//
// Pipeline (Wq/Wo folded into mode domain; no FFT, direct 64-mode DFT):
//  K0 build cos/sin tables  ftT[128][2048] (fwd, -sin on imag plane), it[2048][128] (inv)
//  K1 xfT[b][mc][k]  = sum_l ftT[mc][l] * x[b][l][k]          (GEMM, BT=false)
//  K2 xsel[b][d'][mc]= sum_k Wq[d'][k] * xfT[b][mc][k] (+bq*L if f==0)  (GEMM, BT=true)
//  K3 mode mix per (h,m): out = sum_e xsel * (wr+i wi); writes scaled coefT[b][t][d']
//  K4 zcT[b][n][t]   = sum_d' Wo[n][d'] * coefT[b][t][d']     (GEMM, BT=true)
//  K5 u[b][l][n]     = x + bo + sum_t it[l][t] * zcT[b][n][t] (GEMM, BT=true)
//  K6 r1 = decomp(u)                       (sliding-window moving-avg mixture)
//  K7 h = gelu(r1 @ conv1^T); v = r1 + h @ conv2^T   (chunked over rows)
//  K8 out = decomp(v)
//
// Workspace (time-aliased): [u 64MB][hbuf 32MB]; the K0-K5 scratch
// (tables + mode buffers, 18MB) aliases hbuf's region (dead by K7).

#define EPI_NONE   0
#define EPI_GELU   1
#define EPI_ADDRES 2
#define EPI_INVU   3
#define EPI_WQFOLD 4

__device__ __forceinline__ float gelu_exact(float v) {
    return 0.5f * v * (1.0f + erff(v * 0.70710678118654752f));
}

// C[m,n] = sum_k A[m,k] * (BT ? B[n,k] : B[k,n]),  batched over blockIdx.z.
// 256 threads. TM x TN tile, TK=16, each thread RM x RN.
template<int TM, int TN, int RM, int RN, int EPI, bool BT>
__global__ __launch_bounds__(256)
void sgemm_k(const float* __restrict__ A, long long sA,
             const float* __restrict__ Bm, long long sB,
             float* __restrict__ C, long long sC,
             int M, int N, int K,
             const float* __restrict__ res, long long sRes,
             const float* __restrict__ bias, const int* __restrict__ midx)
{
    constexpr int TK = 16;
    __shared__ __align__(16) float As[TK][TM + 4];
    __shared__ __align__(16) float Bs[TK][TN + 4];

    const int tid = threadIdx.x;
    const int z = blockIdx.z;
    const int m0 = blockIdx.y * TM;
    const int n0 = blockIdx.x * TN;

    A  += (size_t)z * sA;
    Bm += (size_t)z * sB;
    C  += (size_t)z * sC;
    const float* resz = res ? res + (size_t)z * sRes : nullptr;

    constexpr int TX = TN / RN;
    const int tx = tid % TX;
    const int ty = tid / TX;

    float acc[RM][RN];
#pragma unroll
    for (int i = 0; i < RM; ++i)
#pragma unroll
        for (int j = 0; j < RN; ++j) acc[i][j] = 0.0f;

    for (int k0 = 0; k0 < K; k0 += TK) {
        // stage A tile: TK*TM elems, float4 along k, transposed into As[kk][m]
#pragma unroll
        for (int p = 0; p < TM / 64; ++p) {
            int t = tid + p * 256;
            int row = t >> 2;
            int kq = (t & 3) * 4;
            const float4 v = *reinterpret_cast<const float4*>(
                &A[(size_t)(m0 + row) * (size_t)K + (size_t)(k0 + kq)]);
            As[kq + 0][row] = v.x; As[kq + 1][row] = v.y;
            As[kq + 2][row] = v.z; As[kq + 3][row] = v.w;
        }
        if (BT) {
#pragma unroll
            for (int p = 0; p < TN / 64; ++p) {
                int t = tid + p * 256;
                int row = t >> 2;
                int kq = (t & 3) * 4;
                const float4 v = *reinterpret_cast<const float4*>(
                    &Bm[(size_t)(n0 + row) * (size_t)K + (size_t)(k0 + kq)]);
                Bs[kq + 0][row] = v.x; Bs[kq + 1][row] = v.y;
                Bs[kq + 2][row] = v.z; Bs[kq + 3][row] = v.w;
            }
        } else {
#pragma unroll
            for (int p = 0; p < TN / 64; ++p) {
                int t = tid + p * 256;
                int kk = t / (TN / 4);
                int nq = (t % (TN / 4)) * 4;
                const float4 v = *reinterpret_cast<const float4*>(
                    &Bm[(size_t)(k0 + kk) * (size_t)N + (size_t)(n0 + nq)]);
                *reinterpret_cast<float4*>(&Bs[kk][nq]) = v;
            }
        }
        __syncthreads();

#pragma unroll
        for (int kk = 0; kk < TK; ++kk) {
            float a[RM], b[RN];
#pragma unroll
            for (int i = 0; i < RM / 4; ++i)
                *reinterpret_cast<float4*>(&a[i * 4]) =
                    *reinterpret_cast<const float4*>(&As[kk][ty * RM + i * 4]);
#pragma unroll
            for (int j = 0; j < RN / 4; ++j)
                *reinterpret_cast<float4*>(&b[j * 4]) =
                    *reinterpret_cast<const float4*>(&Bs[kk][tx * RN + j * 4]);
#pragma unroll
            for (int i = 0; i < RM; ++i)
#pragma unroll
                for (int j = 0; j < RN; ++j)
                    acc[i][j] = fmaf(a[i], b[j], acc[i][j]);
        }
        __syncthreads();
    }

    // epilogue
#pragma unroll
    for (int i = 0; i < RM; ++i) {
        const int m = m0 + ty * RM + i;
#pragma unroll
        for (int j4 = 0; j4 < RN; j4 += 4) {
            const int n = n0 + tx * RN + j4;
            const size_t idx = (size_t)m * (size_t)N + (size_t)n;
            float tmp[4];
#pragma unroll
            for (int j = 0; j < 4; ++j) {
                float v = acc[i][j4 + j];
                if (EPI == EPI_GELU) {
                    v = gelu_exact(v);
                } else if (EPI == EPI_ADDRES) {
                    v += resz[idx + j];
                } else if (EPI == EPI_INVU) {
                    v += resz[idx + j] + bias[n + j];
                } else if (EPI == EPI_WQFOLD) {
                    int nn = n + j;
                    if (nn < 64 && midx[nn] == 0) v += bias[m] * 2048.0f;
                }
                tmp[j] = v;
            }
            float4 o;
            o.x = tmp[0]; o.y = tmp[1]; o.z = tmp[2]; o.w = tmp[3];
            *reinterpret_cast<float4*>(&C[idx]) = o;
        }
    }
}

// Tables: ftT[t][l] (t<64: cos(2*pi*f_t*l/L); t>=64: -sin), it[l][t] (cos / sin of 2*pi*j*l/L)
__global__ void build_tables_kernel(const int* __restrict__ midx,
                                    float* __restrict__ ftT, float* __restrict__ it_)
{
    const int l = blockIdx.x;      // 0..2047
    const int t = threadIdx.x;     // 0..127
    const int m = t & 63;
    const bool im = t >= 64;
    const float c0 = 6.28318530717958647692f / 2048.0f;

    int f = midx[m];
    int ph = (f * l) & 2047;       // exact periodic reduction
    float s, c;
    sincosf(c0 * (float)ph, &s, &c);
    ftT[(size_t)t * 2048 + l] = im ? -s : c;

    int ph2 = (m * l) & 2047;
    float s2, c2;
    sincosf(c0 * (float)ph2, &s2, &c2);
    it_[(size_t)l * 128 + t] = im ? s2 : c2;
}

// Per (m,h): out[b,o] = sum_e xsel[b,h,e,m] * (wr+i*wi)[h,e,o,m]; write scaled coefT.
__global__ __launch_bounds__(256)
void mode_mix_kernel(const float* __restrict__ xsel,
                     const float* __restrict__ wr, const float* __restrict__ wi,
                     float* __restrict__ coefT)
{
    const int m = blockIdx.x;   // mode position 0..63 (== output bin j)
    const int h = blockIdx.y;   // 0..7
    const int tid = threadIdx.x;

    __shared__ float xr[16][64], xi[16][64];
    __shared__ float wrs[64][65], wis[64][65];

    for (int i = tid; i < 4096; i += 256) {
        int e = i >> 6, o = i & 63;
        size_t g = (((size_t)h * 64 + e) * 64 + o) * 64 + m;
        wrs[e][o] = wr[g];
        wis[e][o] = wi[g];
    }
    for (int i = tid; i < 1024; i += 256) {
        int bb = i >> 6, e = i & 63;
        size_t g = ((size_t)bb * 512 + h * 64 + e) * 128;
        xr[bb][e] = xsel[g + m];
        xi[bb][e] = xsel[g + 64 + m];
    }
    __syncthreads();

    const int o = tid & 63;
    const int bq4 = tid >> 6;
    const float sr = (m == 0) ? (1.0f / 2048.0f) : (2.0f / 2048.0f);
    const float si = (m == 0) ? 0.0f : (-2.0f / 2048.0f);

    for (int q = 0; q < 4; ++q) {
        int bb = bq4 * 4 + q;
        float or_ = 0.f, oi_ = 0.f;
#pragma unroll 16
        for (int e = 0; e < 64; ++e) {
            float xrv = xr[bb][e], xiv = xi[bb][e];
            float wrv = wrs[e][o], wiv = wis[e][o];
            or_ += xrv * wrv - xiv * wiv;
            oi_ += xrv * wiv + xiv * wrv;
        }
        size_t base = ((size_t)bb * 128 + m) * 512 + (size_t)h * 64 + o;
        coefT[base] = or_ * sr;                 // cos coefficient, bin m
        coefT[base + 64 * 512] = oi_ * si;      // sin coefficient, bin m
    }
}

// series decomposition: R = X - sum_k softmax_k(X*w_k+b_k) * movavg_k(X), k in {13,25}
__global__ __launch_bounds__(256)
void decomp_kernel(const float* __restrict__ X, float* __restrict__ R,
                   const float* __restrict__ w, const float* __restrict__ bg)
{
    const int d = blockIdx.x * 256 + threadIdx.x;  // 0..511
    const int l0 = blockIdx.y * 256;
    const int b = blockIdx.z;
    const float w0 = w[0], w1 = w[1], b0 = bg[0], b1 = bg[1];

    const float* Xp = X + (size_t)b * 2048 * 512 + d;
    float* Rp = R + (size_t)b * 2048 * 512 + d;

    float s1 = 0.f, s2 = 0.f;  // window sums, k=13 (pad 6), k=25 (pad 12)
    for (int i = l0 - 12; i <= l0 + 12; ++i) {
        int ic = min(max(i, 0), 2047);
        float v = Xp[(size_t)ic * 512];
        s2 += v;
        if (i >= l0 - 6 && i <= l0 + 6) s1 += v;
    }
    for (int l = l0; l < l0 + 256; ++l) {
        float xv = Xp[(size_t)l * 512];
        float m1 = s1 * (1.0f / 13.0f);
        float m2 = s2 * (1.0f / 25.0f);
        float e0 = xv * w0 + b0, e1 = xv * w1 + b1;
        float mx = fmaxf(e0, e1);
        float g0 = expf(e0 - mx), g1 = expf(e1 - mx);
        float mean = (g0 * m1 + g1 * m2) / (g0 + g1);
        Rp[(size_t)l * 512] = xv - mean;
        s1 += Xp[(size_t)min(l + 7, 2047) * 512] - Xp[(size_t)max(l - 6, 0) * 512];
        s2 += Xp[(size_t)min(l + 13, 2047) * 512] - Xp[(size_t)max(l - 12, 0) * 512];
    }
}

extern "C" void kernel_launch(void* const* d_in, const int* in_sizes, int n_in,
                              void* d_out, int out_size, void* d_ws, size_t ws_size,
                              hipStream_t stream)
{
    const float* x    = (const float*)d_in[0];
    const float* Wq   = (const float*)d_in[1];
    const float* bq   = (const float*)d_in[2];
    // d_in[3..6]: Wk,bk,Wv,bv — dead in the reference, skipped.
    const float* Wo   = (const float*)d_in[7];
    const float* bo   = (const float*)d_in[8];
    const float* fwr  = (const float*)d_in[9];
    const float* fwi  = (const float*)d_in[10];
    const float* c1w  = (const float*)d_in[11];
    const float* c2w  = (const float*)d_in[12];
    const float* d1w  = (const float*)d_in[13];
    const float* d1b  = (const float*)d_in[14];
    const float* d2w  = (const float*)d_in[15];
    const float* d2b  = (const float*)d_in[16];
    const int*   midx = (const int*)d_in[17];
    float* out = (float*)d_out;
    float* ws  = (float*)d_ws;

    // Persistent across whole call:
    float* u     = ws;                    // 16*2048*512   = 16777216 floats (64MB)
    // K7-only region (32MB), time-aliased with the K0-K5 scratch below:
    float* hbuf  = u + 16777216;          // 4096*2048     = 8388608 floats
    // K0-K5 scratch (18MB total), aliases hbuf's region (dead by K7):
    float* ftT   = hbuf;                  // 128*2048      = 262144
    float* itT   = ftT   + 262144;        // 2048*128      = 262144
    float* xfT   = itT   + 262144;        // 16*128*512    = 1048576
    float* xsel  = xfT   + 1048576;       // 16*512*128
    float* coefT = xsel  + 1048576;       // 16*128*512
    float* zcT   = coefT + 1048576;       // 16*512*128

    const long long sBL = (long long)2048 * 512;   // per-batch stride of [L,D] tensors
    const long long sP  = 65536;                   // per-batch stride of [128,512]/[512,128]

    // K0: tables
    build_tables_kernel<<<2048, 128, 0, stream>>>(midx, ftT, itT);

    // K1: xfT[b][mc][k] = sum_l ftT[mc][l] * x[b][l][k]   (M=128,N=512,K=2048)
    sgemm_k<64, 64, 4, 4, EPI_NONE, false><<<dim3(8, 2, 16), 256, 0, stream>>>(
        ftT, 0, x, sBL, xfT, sP, 128, 512, 2048, nullptr, 0, nullptr, nullptr);

    // K2: xsel[b][d'][mc] = sum_k Wq[d'][k] * xfT[b][mc][k]  (M=512,N=128,K=512)
    sgemm_k<64, 64, 4, 4, EPI_WQFOLD, true><<<dim3(2, 8, 16), 256, 0, stream>>>(
        Wq, 0, xfT, sP, xsel, sP, 512, 128, 512, nullptr, 0, bq, midx);

    // K3: mode mixing -> scaled inverse coefficients coefT[b][t][d']
    mode_mix_kernel<<<dim3(64, 8), 256, 0, stream>>>(xsel, fwr, fwi, coefT);

    // K4: zcT[b][n][t] = sum_d' Wo[n][d'] * coefT[b][t][d']  (M=512,N=128,K=512)
    sgemm_k<64, 64, 4, 4, EPI_NONE, true><<<dim3(2, 8, 16), 256, 0, stream>>>(
        Wo, 0, coefT, sP, zcT, sP, 512, 128, 512, nullptr, 0, nullptr, nullptr);

    // K5: u[b][l][n] = x + bo + sum_t it[l][t] * zcT[b][n][t]  (M=2048,N=512,K=128)
    sgemm_k<64, 64, 4, 4, EPI_INVU, true><<<dim3(8, 32, 16), 256, 0, stream>>>(
        itT, 0, zcT, sP, u, sBL, 2048, 512, 128, x, sBL, bo, nullptr);

    // K6: r1 = decomp(u)  -> staged in d_out
    decomp_kernel<<<dim3(2, 8, 16), 256, 0, stream>>>(u, out, d1w, d1b);

    // K7: FFN in 8 row-chunks of 4096; v = r1 + gelu(r1@c1^T)@c2^T  -> overwrites u
    for (int c = 0; c < 8; ++c) {
        const float* r1c = out + (size_t)c * 4096 * 512;
        float* vc = u + (size_t)c * 4096 * 512;
        sgemm_k<128, 128, 8, 8, EPI_GELU, true><<<dim3(16, 32, 1), 256, 0, stream>>>(
            r1c, 0, c1w, 0, hbuf, 0, 4096, 2048, 512, nullptr, 0, nullptr, nullptr);
        sgemm_k<128, 128, 8, 8, EPI_ADDRES, true><<<dim3(4, 32, 1), 256, 0, stream>>>(
            hbuf, 0, c2w, 0, vc, 0, 4096, 512, 2048, r1c, 0, nullptr, nullptr);
    }

    // K8: out = decomp(v)
    decomp_kernel<<<dim3(2, 8, 16), 256, 0, stream>>>(u, out, d2w, d2b);
}

// Round 4
// 1301.255 us; speedup vs baseline: 2.5576x; 2.5576x over previous
//
#include <hip/hip_runtime.h>
#include <math.h>

// FEDformer encoder layer, MI355X. B=16, L=2048, D=512, H=8, E=64, M=64, DFF=2048.
// Round 3: FFN on split-bf16 MFMA. h kept as single bf16 plane (weights stay hi+lo);
// GEMM2 uses BN=64 tiles for full-grid occupancy. Phase 1 (DFT path) fp32 unchanged.
//
//  K0-K5: DFT path -> u (fp32, ws region0)
//  K6:    decomp(u) -> r1 hi/lo bf16 planes in d_out
//  W:     conv1/conv2 weights -> hi/lo bf16 planes
//  per chunk c (R=4096 rows):
//    G1: h = gelu(r1@c1^T)   (3-pass MFMA: AhBh+AhBl+AlBh) -> h bf16 plane (ws)
//    G2: v = r1 + h@c2^T     (2-pass MFMA: AhBh+AhBl)      -> v fp32 (region0)
//  K8:    decomp(v) -> d_out (fp32)

#define EPI_NONE   0
#define EPI_INVU   3
#define EPI_WQFOLD 4

typedef __attribute__((ext_vector_type(8))) short short8;
typedef __attribute__((ext_vector_type(4))) float f32x4;

#define AS1 __attribute__((address_space(1)))
#define AS3 __attribute__((address_space(3)))

__device__ __forceinline__ void gll16(const void* g, void* l) {
    __builtin_amdgcn_global_load_lds((const AS1 void*)g, (AS3 void*)l, 16, 0, 0);
}

__device__ __forceinline__ float gelu_exact(float v) {
    return 0.5f * v * (1.0f + erff(v * 0.70710678118654752f));
}

__device__ __forceinline__ unsigned short f2bf(float f) {
    unsigned u = __builtin_bit_cast(unsigned, f);
    unsigned r = (u + 0x7fffu + ((u >> 16) & 1u)) >> 16;
    return (unsigned short)r;
}
__device__ __forceinline__ float bf2f(unsigned short h) {
    unsigned u = ((unsigned)h) << 16;
    return __builtin_bit_cast(float, u);
}

// ---------------- split-bf16 MFMA GEMM ----------------
// C[m,n] = sum_k A(m,k)*B(n,k); A hi(/lo if ALO) planes, B hi+lo planes, row stride K.
// BM=128 x BN tile, BK=32, 256 thr = 4 waves (2x2), wave tile 64 x BN/2.
// LDS rows are 64B = 4 x 16B slots; physical slot = logical ^ ((row>>1)&3)
// (inverse swizzle applied on the global source; 2-way bank alias on reads = free).
// EPI 1: gelu -> bf16 plane Ch (stride N). EPI 2: + residual(Rh+Rl) -> fp32 Cf.
template<int BN, int EPI, bool ALO>
__global__ __launch_bounds__(256)
void gemm_hl(const unsigned short* __restrict__ Ah, const unsigned short* __restrict__ Al,
             const unsigned short* __restrict__ Bh, const unsigned short* __restrict__ Bl,
             float* __restrict__ Cf, unsigned short* __restrict__ Ch,
             const unsigned short* __restrict__ Rh, const unsigned short* __restrict__ Rl,
             int N, int K)
{
    constexpr int NJ = BN / 32;            // b-fragments per wave (wave n-tile = BN/2)
    __shared__ __align__(16) unsigned short sA[ALO ? 2 : 1][128 * 32];
    __shared__ __align__(16) unsigned short sB[2][BN * 32];

    const int tid  = threadIdx.x;
    const int lane = tid & 63;
    const int wid  = tid >> 6;
    const int wm   = wid >> 1, wn = wid & 1;
    const int m0   = blockIdx.y * 128;
    const int n0   = blockIdx.x * BN;

    f32x4 acc[4][NJ] = {};

    // A staging: 8 chunks of 16 rows; wave stages chunks wid*2, wid*2+1.
    const int srA0 = wid * 32 + (lane >> 2);
    const int srA1 = srA0 + 16;
    const int lsA0 = (lane & 3) ^ ((srA0 >> 1) & 3);
    const int lsA1 = (lane & 3) ^ ((srA1 >> 1) & 3);
    // B staging: BN==128 -> same pattern; BN==64 -> 4 chunks, one per wave.
    const int srB0 = (BN == 128) ? srA0 : (wid * 16 + (lane >> 2));
    const int srB1 = srA1;  // only used when BN==128
    const int lsB0 = (lane & 3) ^ ((srB0 >> 1) & 3);
    const int lsB1 = lsA1;

    for (int k0 = 0; k0 < K; k0 += 32) {
        size_t gA0 = (size_t)(m0 + srA0) * K + k0 + lsA0 * 8;
        size_t gA1 = (size_t)(m0 + srA1) * K + k0 + lsA1 * 8;
        gll16(Ah + gA0, &sA[0][(wid * 2 + 0) * 512]);
        gll16(Ah + gA1, &sA[0][(wid * 2 + 1) * 512]);
        if (ALO) {
            gll16(Al + gA0, &sA[1][(wid * 2 + 0) * 512]);
            gll16(Al + gA1, &sA[1][(wid * 2 + 1) * 512]);
        }
        size_t gB0 = (size_t)(n0 + srB0) * K + k0 + lsB0 * 8;
        gll16(Bh + gB0, &sB[0][(BN == 128 ? wid * 2 : wid) * 512]);
        gll16(Bl + gB0, &sB[1][(BN == 128 ? wid * 2 : wid) * 512]);
        if (BN == 128) {
            size_t gB1 = (size_t)(n0 + srB1) * K + k0 + lsB1 * 8;
            gll16(Bh + gB1, &sB[0][(wid * 2 + 1) * 512]);
            gll16(Bl + gB1, &sB[1][(wid * 2 + 1) * 512]);
        }
        __syncthreads();

        short8 a[ALO ? 2 : 1][4], b[2][NJ];
        const int s = lane >> 4;
#pragma unroll
        for (int i = 0; i < 4; ++i) {
            int r = wm * 64 + i * 16 + (lane & 15);
            int off = r * 32 + (s ^ ((r >> 1) & 3)) * 8;
            a[0][i] = *reinterpret_cast<const short8*>(&sA[0][off]);
            if (ALO) a[1][i] = *reinterpret_cast<const short8*>(&sA[1][off]);
        }
#pragma unroll
        for (int j = 0; j < NJ; ++j) {
            int rn = wn * (BN / 2) + j * 16 + (lane & 15);
            int offn = rn * 32 + (s ^ ((rn >> 1) & 3)) * 8;
            b[0][j] = *reinterpret_cast<const short8*>(&sB[0][offn]);
            b[1][j] = *reinterpret_cast<const short8*>(&sB[1][offn]);
        }
#pragma unroll
        for (int i = 0; i < 4; ++i)
#pragma unroll
            for (int j = 0; j < NJ; ++j) {
                acc[i][j] = __builtin_amdgcn_mfma_f32_16x16x32_bf16(a[0][i], b[0][j], acc[i][j], 0, 0, 0);
                acc[i][j] = __builtin_amdgcn_mfma_f32_16x16x32_bf16(a[0][i], b[1][j], acc[i][j], 0, 0, 0);
                if (ALO)
                    acc[i][j] = __builtin_amdgcn_mfma_f32_16x16x32_bf16(a[1][i], b[0][j], acc[i][j], 0, 0, 0);
            }
        __syncthreads();
    }

    // C/D layout (m89-verified): col = lane&15, row = (lane>>4)*4 + reg
    const int cr = (lane >> 4) * 4;
    const int cc = lane & 15;
#pragma unroll
    for (int i = 0; i < 4; ++i)
#pragma unroll
        for (int j = 0; j < NJ; ++j)
#pragma unroll
            for (int r = 0; r < 4; ++r) {
                int m = m0 + wm * 64 + i * 16 + cr + r;
                int n = n0 + wn * (BN / 2) + j * 16 + cc;
                size_t idx = (size_t)m * N + n;
                float v = acc[i][j][r];
                if (EPI == 1) {
                    Ch[idx] = f2bf(gelu_exact(v));
                } else {
                    Cf[idx] = v + bf2f(Rh[idx]) + bf2f(Rl[idx]);
                }
            }
}

// fp32 -> hi/lo bf16 planes (weights), float4 path
__global__ __launch_bounds__(256)
void split_f32_kernel(const float* __restrict__ src, unsigned short* __restrict__ hi,
                      unsigned short* __restrict__ lo, int n4)
{
    int i = blockIdx.x * 256 + threadIdx.x;
    if (i >= n4) return;
    float4 v = reinterpret_cast<const float4*>(src)[i];
    ushort4 h, l;
    h.x = f2bf(v.x); l.x = f2bf(v.x - bf2f(h.x));
    h.y = f2bf(v.y); l.y = f2bf(v.y - bf2f(h.y));
    h.z = f2bf(v.z); l.z = f2bf(v.z - bf2f(h.z));
    h.w = f2bf(v.w); l.w = f2bf(v.w - bf2f(h.w));
    reinterpret_cast<ushort4*>(hi)[i] = h;
    reinterpret_cast<ushort4*>(lo)[i] = l;
}

// ---------------- fp32 GEMM (phase 1) ----------------
template<int TM, int TN, int RM, int RN, int EPI, bool BT>
__global__ __launch_bounds__(256)
void sgemm_k(const float* __restrict__ A, long long sA,
             const float* __restrict__ Bm, long long sB,
             float* __restrict__ C, long long sC,
             int M, int N, int K,
             const float* __restrict__ res, long long sRes,
             const float* __restrict__ bias, const int* __restrict__ midx)
{
    constexpr int TK = 16;
    __shared__ __align__(16) float As[TK][TM + 4];
    __shared__ __align__(16) float Bs[TK][TN + 4];

    const int tid = threadIdx.x;
    const int z = blockIdx.z;
    const int m0 = blockIdx.y * TM;
    const int n0 = blockIdx.x * TN;

    A  += (size_t)z * sA;
    Bm += (size_t)z * sB;
    C  += (size_t)z * sC;
    const float* resz = res ? res + (size_t)z * sRes : nullptr;

    constexpr int TX = TN / RN;
    const int tx = tid % TX;
    const int ty = tid / TX;

    float acc[RM][RN];
#pragma unroll
    for (int i = 0; i < RM; ++i)
#pragma unroll
        for (int j = 0; j < RN; ++j) acc[i][j] = 0.0f;

    for (int k0 = 0; k0 < K; k0 += TK) {
#pragma unroll
        for (int p = 0; p < TM / 64; ++p) {
            int t = tid + p * 256;
            int row = t >> 2;
            int kq = (t & 3) * 4;
            const float4 v = *reinterpret_cast<const float4*>(
                &A[(size_t)(m0 + row) * (size_t)K + (size_t)(k0 + kq)]);
            As[kq + 0][row] = v.x; As[kq + 1][row] = v.y;
            As[kq + 2][row] = v.z; As[kq + 3][row] = v.w;
        }
        if (BT) {
#pragma unroll
            for (int p = 0; p < TN / 64; ++p) {
                int t = tid + p * 256;
                int row = t >> 2;
                int kq = (t & 3) * 4;
                const float4 v = *reinterpret_cast<const float4*>(
                    &Bm[(size_t)(n0 + row) * (size_t)K + (size_t)(k0 + kq)]);
                Bs[kq + 0][row] = v.x; Bs[kq + 1][row] = v.y;
                Bs[kq + 2][row] = v.z; Bs[kq + 3][row] = v.w;
            }
        } else {
#pragma unroll
            for (int p = 0; p < TN / 64; ++p) {
                int t = tid + p * 256;
                int kk = t / (TN / 4);
                int nq = (t % (TN / 4)) * 4;
                const float4 v = *reinterpret_cast<const float4*>(
                    &Bm[(size_t)(k0 + kk) * (size_t)N + (size_t)(n0 + nq)]);
                *reinterpret_cast<float4*>(&Bs[kk][nq]) = v;
            }
        }
        __syncthreads();

#pragma unroll
        for (int kk = 0; kk < TK; ++kk) {
            float a[RM], b[RN];
#pragma unroll
            for (int i = 0; i < RM / 4; ++i)
                *reinterpret_cast<float4*>(&a[i * 4]) =
                    *reinterpret_cast<const float4*>(&As[kk][ty * RM + i * 4]);
#pragma unroll
            for (int j = 0; j < RN / 4; ++j)
                *reinterpret_cast<float4*>(&b[j * 4]) =
                    *reinterpret_cast<const float4*>(&Bs[kk][tx * RN + j * 4]);
#pragma unroll
            for (int i = 0; i < RM; ++i)
#pragma unroll
                for (int j = 0; j < RN; ++j)
                    acc[i][j] = fmaf(a[i], b[j], acc[i][j]);
        }
        __syncthreads();
    }

#pragma unroll
    for (int i = 0; i < RM; ++i) {
        const int m = m0 + ty * RM + i;
#pragma unroll
        for (int j4 = 0; j4 < RN; j4 += 4) {
            const int n = n0 + tx * RN + j4;
            const size_t idx = (size_t)m * (size_t)N + (size_t)n;
            float tmp[4];
#pragma unroll
            for (int j = 0; j < 4; ++j) {
                float v = acc[i][j4 + j];
                if (EPI == EPI_INVU) {
                    v += resz[idx + j] + bias[n + j];
                } else if (EPI == EPI_WQFOLD) {
                    int nn = n + j;
                    if (nn < 64 && midx[nn] == 0) v += bias[m] * 2048.0f;
                }
                tmp[j] = v;
            }
            float4 o;
            o.x = tmp[0]; o.y = tmp[1]; o.z = tmp[2]; o.w = tmp[3];
            *reinterpret_cast<float4*>(&C[idx]) = o;
        }
    }
}

__global__ void build_tables_kernel(const int* __restrict__ midx,
                                    float* __restrict__ ftT, float* __restrict__ it_)
{
    const int l = blockIdx.x;
    const int t = threadIdx.x;
    const int m = t & 63;
    const bool im = t >= 64;
    const float c0 = 6.28318530717958647692f / 2048.0f;

    int f = midx[m];
    int ph = (f * l) & 2047;
    float s, c;
    sincosf(c0 * (float)ph, &s, &c);
    ftT[(size_t)t * 2048 + l] = im ? -s : c;

    int ph2 = (m * l) & 2047;
    float s2, c2;
    sincosf(c0 * (float)ph2, &s2, &c2);
    it_[(size_t)l * 128 + t] = im ? s2 : c2;
}

__global__ __launch_bounds__(256)
void mode_mix_kernel(const float* __restrict__ xsel,
                     const float* __restrict__ wr, const float* __restrict__ wi,
                     float* __restrict__ coefT)
{
    const int m = blockIdx.x;
    const int h = blockIdx.y;
    const int tid = threadIdx.x;

    __shared__ float xr[16][64], xi[16][64];
    __shared__ float wrs[64][65], wis[64][65];

    for (int i = tid; i < 4096; i += 256) {
        int e = i >> 6, o = i & 63;
        size_t g = (((size_t)h * 64 + e) * 64 + o) * 64 + m;
        wrs[e][o] = wr[g];
        wis[e][o] = wi[g];
    }
    for (int i = tid; i < 1024; i += 256) {
        int bb = i >> 6, e = i & 63;
        size_t g = ((size_t)bb * 512 + h * 64 + e) * 128;
        xr[bb][e] = xsel[g + m];
        xi[bb][e] = xsel[g + 64 + m];
    }
    __syncthreads();

    const int o = tid & 63;
    const int bq4 = tid >> 6;
    const float sr = (m == 0) ? (1.0f / 2048.0f) : (2.0f / 2048.0f);
    const float si = (m == 0) ? 0.0f : (-2.0f / 2048.0f);

    for (int q = 0; q < 4; ++q) {
        int bb = bq4 * 4 + q;
        float or_ = 0.f, oi_ = 0.f;
#pragma unroll 16
        for (int e = 0; e < 64; ++e) {
            float xrv = xr[bb][e], xiv = xi[bb][e];
            float wrv = wrs[e][o], wiv = wis[e][o];
            or_ += xrv * wrv - xiv * wiv;
            oi_ += xrv * wiv + xiv * wrv;
        }
        size_t base = ((size_t)bb * 128 + m) * 512 + (size_t)h * 64 + o;
        coefT[base] = or_ * sr;
        coefT[base + 64 * 512] = oi_ * si;
    }
}

// decomp: R = X - sum_k softmax_k(X*w_k+b_k)*movavg_k(X). SPLIT: write hi/lo planes.
template<bool SPLIT>
__global__ __launch_bounds__(256)
void decomp_kernel(const float* __restrict__ X, float* __restrict__ Rf,
                   unsigned short* __restrict__ Rh, unsigned short* __restrict__ Rl,
                   const float* __restrict__ w, const float* __restrict__ bg)
{
    const int d = blockIdx.x * 256 + threadIdx.x;
    const int l0 = blockIdx.y * 256;
    const int b = blockIdx.z;
    const float w0 = w[0], w1 = w[1], b0 = bg[0], b1 = bg[1];

    const float* Xp = X + (size_t)b * 2048 * 512 + d;
    const size_t obase = (size_t)b * 2048 * 512 + d;

    float s1 = 0.f, s2 = 0.f;
    for (int i = l0 - 12; i <= l0 + 12; ++i) {
        int ic = min(max(i, 0), 2047);
        float v = Xp[(size_t)ic * 512];
        s2 += v;
        if (i >= l0 - 6 && i <= l0 + 6) s1 += v;
    }
    for (int l = l0; l < l0 + 256; ++l) {
        float xv = Xp[(size_t)l * 512];
        float m1 = s1 * (1.0f / 13.0f);
        float m2 = s2 * (1.0f / 25.0f);
        float e0 = xv * w0 + b0, e1 = xv * w1 + b1;
        float mx = fmaxf(e0, e1);
        float g0 = expf(e0 - mx), g1 = expf(e1 - mx);
        float mean = (g0 * m1 + g1 * m2) / (g0 + g1);
        float rv = xv - mean;
        size_t oi = obase + (size_t)l * 512;
        if (SPLIT) {
            unsigned short h = f2bf(rv);
            Rh[oi] = h;
            Rl[oi] = f2bf(rv - bf2f(h));
        } else {
            Rf[oi] = rv;
        }
        s1 += Xp[(size_t)min(l + 7, 2047) * 512] - Xp[(size_t)max(l - 6, 0) * 512];
        s2 += Xp[(size_t)min(l + 13, 2047) * 512] - Xp[(size_t)max(l - 12, 0) * 512];
    }
}

extern "C" void kernel_launch(void* const* d_in, const int* in_sizes, int n_in,
                              void* d_out, int out_size, void* d_ws, size_t ws_size,
                              hipStream_t stream)
{
    const float* x    = (const float*)d_in[0];
    const float* Wq   = (const float*)d_in[1];
    const float* bq   = (const float*)d_in[2];
    const float* Wo   = (const float*)d_in[7];
    const float* bo   = (const float*)d_in[8];
    const float* fwr  = (const float*)d_in[9];
    const float* fwi  = (const float*)d_in[10];
    const float* c1w  = (const float*)d_in[11];
    const float* c2w  = (const float*)d_in[12];
    const float* d1w  = (const float*)d_in[13];
    const float* d1b  = (const float*)d_in[14];
    const float* d2w  = (const float*)d_in[15];
    const float* d2b  = (const float*)d_in[16];
    const int*   midx = (const int*)d_in[17];
    float* out = (float*)d_out;
    float* ws  = (float*)d_ws;

    // ws layout (<= 96MB, proven available):
    //  [0   : 64MB)  region0: u (phase1) -> v (phase2)          16777216 f32
    //  [64MB: 72MB)  weight planes c1h,c1l,c2h,c2l (4 x 1048576 ushort)
    //  [72MB: 88MB)  h bf16 plane, chunk R=4096 x 2048; phase-1 scratch (18MB) aliases
    float* region0 = ws;
    unsigned short* wsp = (unsigned short*)(ws + 16777216);
    unsigned short* c1h = wsp;
    unsigned short* c1l = wsp + 1048576;
    unsigned short* c2h = wsp + 2 * 1048576;
    unsigned short* c2l = wsp + 3 * 1048576;
    float* scratch = ws + 18874368;            // 72MB offset
    unsigned short* hh = (unsigned short*)scratch;
    const int R = 4096;                        // FFN chunk rows (h plane = 16MB)

    // phase-1 scratch (floats), aliases h region (dead before first GEMM1)
    float* ftT   = scratch;
    float* itT   = ftT   + 262144;
    float* xfT   = itT   + 262144;
    float* xsel  = xfT   + 1048576;
    float* coefT = xsel  + 1048576;
    float* zcT   = coefT + 1048576;

    // r1 hi/lo planes live in d_out until K8 (d_out fully rewritten by K8)
    unsigned short* r1h = (unsigned short*)d_out;
    unsigned short* r1l = r1h + 16777216;

    const long long sBL = (long long)2048 * 512;
    const long long sP  = 65536;

    // W: weight planes
    split_f32_kernel<<<1024, 256, 0, stream>>>(c1w, c1h, c1l, 262144);
    split_f32_kernel<<<1024, 256, 0, stream>>>(c2w, c2h, c2l, 262144);

    // K0: tables
    build_tables_kernel<<<2048, 128, 0, stream>>>(midx, ftT, itT);

    // K1: xfT[b][mc][k] = sum_l ftT[mc][l] * x[b][l][k]
    sgemm_k<64, 64, 4, 4, EPI_NONE, false><<<dim3(8, 2, 16), 256, 0, stream>>>(
        ftT, 0, x, sBL, xfT, sP, 128, 512, 2048, nullptr, 0, nullptr, nullptr);

    // K2: xsel[b][d'][mc] = sum_k Wq[d'][k] * xfT[b][mc][k]
    sgemm_k<64, 64, 4, 4, EPI_WQFOLD, true><<<dim3(2, 8, 16), 256, 0, stream>>>(
        Wq, 0, xfT, sP, xsel, sP, 512, 128, 512, nullptr, 0, bq, midx);

    // K3: mode mixing
    mode_mix_kernel<<<dim3(64, 8), 256, 0, stream>>>(xsel, fwr, fwi, coefT);

    // K4: zcT[b][n][t] = sum_d' Wo[n][d'] * coefT[b][t][d']
    sgemm_k<64, 64, 4, 4, EPI_NONE, true><<<dim3(2, 8, 16), 256, 0, stream>>>(
        Wo, 0, coefT, sP, zcT, sP, 512, 128, 512, nullptr, 0, nullptr, nullptr);

    // K5: u[b][l][n] = x + bo + sum_t it[l][t] * zcT[b][n][t]
    sgemm_k<64, 64, 4, 4, EPI_INVU, true><<<dim3(8, 32, 16), 256, 0, stream>>>(
        itT, 0, zcT, sP, region0, sBL, 2048, 512, 128, x, sBL, bo, nullptr);

    // K6: r1 = decomp(u) -> hi/lo planes in d_out
    decomp_kernel<true><<<dim3(2, 8, 16), 256, 0, stream>>>(
        region0, nullptr, r1h, r1l, d1w, d1b);

    // FFN chunks (split-bf16 MFMA); u dead -> region0 receives v
    const int nc = 32768 / R;
    for (int c = 0; c < nc; ++c) {
        const unsigned short* r1hc = r1h + (size_t)c * R * 512;
        const unsigned short* r1lc = r1l + (size_t)c * R * 512;
        gemm_hl<128, 1, true><<<dim3(16, R / 128), 256, 0, stream>>>(
            r1hc, r1lc, c1h, c1l, nullptr, hh, nullptr, nullptr, 2048, 512);
        gemm_hl<64, 2, false><<<dim3(8, R / 128), 256, 0, stream>>>(
            hh, nullptr, c2h, c2l, region0 + (size_t)c * R * 512, nullptr,
            r1hc, r1lc, 512, 2048);
    }

    // K8: out = decomp(v)
    decomp_kernel<false><<<dim3(2, 8, 16), 256, 0, stream>>>(
        region0, out, nullptr, nullptr, d2w, d2b);
}

// Round 5
// 1117.992 us; speedup vs baseline: 2.9768x; 1.1639x over previous
//
#include <hip/hip_runtime.h>
#include <math.h>

// FEDformer encoder layer, MI355X. B=16, L=2048, D=512, H=8, E=64, M=64, DFF=2048.
// Round 4: ALL GEMMs on split-bf16 MFMA (3-pass hi/lo). Phase-1 tables/weights are
// built/split into bf16 hi/lo planes; K1 reg-stage-transposes x into LDS.
//
//  T:  tables -> ft/it hi+lo planes; split Wq,Wo
//  K1 gemm_dft: xf[b][t][d] = sum_l ft[t][l]*x[b][l][d]        -> xf planes
//  K2 gemm_hl<64,64,WQFOLD>: xsel[b][d'][mc] = Wq @ xf^T        -> fp32
//  K3 mode_mix -> coef planes
//  K4 gemm_hl<64,64,SPLIT>:  zc[b][n][t] = Wo @ coef^T          -> zc planes
//  K5 gemm_hl<128,64,INVU>:  u = x + bo + it @ zc^T             -> u fp32
//  K6 decomp(u) -> r1 hi/lo planes (d_out)
//  split c1,c2 -> planes;  per chunk (R=4096): G1 gelu GEMM -> h plane; G2 res GEMM -> v
//  K8 decomp(v) -> out

#define EPI_GELU   1
#define EPI_RES    2
#define EPI_SPLIT  3
#define EPI_WQFOLD 4
#define EPI_INVU   5

typedef __attribute__((ext_vector_type(8))) short short8;
typedef __attribute__((ext_vector_type(4))) float f32x4;

#define AS1 __attribute__((address_space(1)))
#define AS3 __attribute__((address_space(3)))

__device__ __forceinline__ void gll16(const void* g, void* l) {
    __builtin_amdgcn_global_load_lds((const AS1 void*)g, (AS3 void*)l, 16, 0, 0);
}

__device__ __forceinline__ float gelu_exact(float v) {
    return 0.5f * v * (1.0f + erff(v * 0.70710678118654752f));
}

__device__ __forceinline__ unsigned short f2bf(float f) {
    unsigned u = __builtin_bit_cast(unsigned, f);
    unsigned r = (u + 0x7fffu + ((u >> 16) & 1u)) >> 16;
    return (unsigned short)r;
}
__device__ __forceinline__ float bf2f(unsigned short h) {
    unsigned u = ((unsigned)h) << 16;
    return __builtin_bit_cast(float, u);
}

// ---------------- generalized split-bf16 MFMA GEMM ----------------
// C[m,n] = sum_k A(m,k)*B(n,k); A,B bf16 plane pairs (k-contig rows, stride K).
// BM x BN tile, BK=32, 4 waves (2x2), wave tile (BM/2)x(BN/2), 16x16x32 frags.
// LDS chunk = 16 rows x 32 cols bf16 = 1KB staged by one gll16 (lane -> row l>>2,
// phys slot l&3; logical slot = phys ^ ((row>>1)&3) applied on the global source).
template<int BM, int BN, int EPI, bool ALO, bool BLO>
__global__ __launch_bounds__(256)
void gemm_hl(const unsigned short* __restrict__ Ah, const unsigned short* __restrict__ Al, long long sAb,
             const unsigned short* __restrict__ Bh, const unsigned short* __restrict__ Bl, long long sBb,
             float* __restrict__ Cf, unsigned short* __restrict__ Ch, unsigned short* __restrict__ Cl,
             long long sCb,
             const unsigned short* __restrict__ Rh, const unsigned short* __restrict__ Rl,
             const float* __restrict__ resf, long long sRb,
             const float* __restrict__ bias, const int* __restrict__ midx,
             int N, int K)
{
    constexpr int MI = BM / 32, NJ = BN / 32;
    __shared__ __align__(16) unsigned short sA[ALO ? 2 : 1][BM * 32];
    __shared__ __align__(16) unsigned short sB[BLO ? 2 : 1][BN * 32];

    const int tid = threadIdx.x, lane = tid & 63, wid = tid >> 6;
    const int wm = wid >> 1, wn = wid & 1;
    const int m0 = blockIdx.y * BM, n0 = blockIdx.x * BN;
    const int z = blockIdx.z;

    Ah += (size_t)z * sAb; if (ALO) Al += (size_t)z * sAb;
    Bh += (size_t)z * sBb; if (BLO) Bl += (size_t)z * sBb;

    f32x4 acc[MI][NJ] = {};

    const int srr = lane >> 2;   // row within 16-row chunk
    const int sp  = lane & 3;    // physical 16B slot

    for (int k0 = 0; k0 < K; k0 += 32) {
        for (int ch = wid; ch < BM / 16; ch += 4) {
            int row = ch * 16 + srr;
            int ls = sp ^ ((row >> 1) & 3);
            size_t g = (size_t)(m0 + row) * K + k0 + ls * 8;
            gll16(Ah + g, &sA[0][ch * 512]);
            if (ALO) gll16(Al + g, &sA[1][ch * 512]);
        }
        for (int ch = wid; ch < BN / 16; ch += 4) {
            int row = ch * 16 + srr;
            int ls = sp ^ ((row >> 1) & 3);
            size_t g = (size_t)(n0 + row) * K + k0 + ls * 8;
            gll16(Bh + g, &sB[0][ch * 512]);
            if (BLO) gll16(Bl + g, &sB[1][ch * 512]);
        }
        __syncthreads();

        short8 a[ALO ? 2 : 1][MI], b[BLO ? 2 : 1][NJ];
        const int s = lane >> 4;
#pragma unroll
        for (int i = 0; i < MI; ++i) {
            int r = wm * (BM / 2) + i * 16 + (lane & 15);
            int off = r * 32 + (s ^ ((r >> 1) & 3)) * 8;
            a[0][i] = *reinterpret_cast<const short8*>(&sA[0][off]);
            if (ALO) a[1][i] = *reinterpret_cast<const short8*>(&sA[1][off]);
        }
#pragma unroll
        for (int j = 0; j < NJ; ++j) {
            int r = wn * (BN / 2) + j * 16 + (lane & 15);
            int off = r * 32 + (s ^ ((r >> 1) & 3)) * 8;
            b[0][j] = *reinterpret_cast<const short8*>(&sB[0][off]);
            if (BLO) b[1][j] = *reinterpret_cast<const short8*>(&sB[1][off]);
        }
#pragma unroll
        for (int i = 0; i < MI; ++i)
#pragma unroll
            for (int j = 0; j < NJ; ++j) {
                acc[i][j] = __builtin_amdgcn_mfma_f32_16x16x32_bf16(a[0][i], b[0][j], acc[i][j], 0, 0, 0);
                if (BLO)
                    acc[i][j] = __builtin_amdgcn_mfma_f32_16x16x32_bf16(a[0][i], b[1][j], acc[i][j], 0, 0, 0);
                if (ALO)
                    acc[i][j] = __builtin_amdgcn_mfma_f32_16x16x32_bf16(a[1][i], b[0][j], acc[i][j], 0, 0, 0);
            }
        __syncthreads();
    }

    // C/D layout (m89-verified): col = lane&15, row = (lane>>4)*4 + reg
    const int cr = (lane >> 4) * 4, cc = lane & 15;
#pragma unroll
    for (int i = 0; i < MI; ++i)
#pragma unroll
        for (int j = 0; j < NJ; ++j)
#pragma unroll
            for (int r = 0; r < 4; ++r) {
                int m = m0 + wm * (BM / 2) + i * 16 + cr + r;
                int n = n0 + wn * (BN / 2) + j * 16 + cc;
                size_t idx = (size_t)z * sCb + (size_t)m * N + n;
                float v = acc[i][j][r];
                if (EPI == EPI_GELU) {
                    Ch[idx] = f2bf(gelu_exact(v));
                } else if (EPI == EPI_RES) {
                    size_t ri = (size_t)m * N + n;
                    Cf[idx] = v + bf2f(Rh[ri]) + bf2f(Rl[ri]);
                } else if (EPI == EPI_SPLIT) {
                    unsigned short h = f2bf(v);
                    Ch[idx] = h;
                    Cl[idx] = f2bf(v - bf2f(h));
                } else if (EPI == EPI_WQFOLD) {
                    if (n < 64 && midx[n] == 0) v += bias[m] * 2048.0f;
                    Cf[idx] = v;
                } else if (EPI == EPI_INVU) {
                    size_t ri = (size_t)z * sRb + (size_t)m * N + n;
                    Cf[idx] = v + resf[ri] + bias[n];
                }
            }
}

// ---------------- K1: forward DFT GEMM with in-stage transpose+split of x ----------------
// xf[t][d] = sum_l ft[t][l] * x[l][d].  A = ft planes (k-contig, gll16).
// B = x fp32 [l][d]: reg-staged, transposed+split into LDS [d][l] u32 l-pairs, pitch 20.
__global__ __launch_bounds__(256)
void gemm_dft(const unsigned short* __restrict__ Ath, const unsigned short* __restrict__ Atl,
              const float* __restrict__ X, long long sXb,
              unsigned short* __restrict__ Oh, unsigned short* __restrict__ Ol, long long sOb)
{
    __shared__ __align__(16) unsigned short sA[2][64 * 32];
    __shared__ __align__(16) unsigned sB[2][64 * 20];   // [d][20 u32], 16 used = 32 l

    const int tid = threadIdx.x, lane = tid & 63, wid = tid >> 6;
    const int wm = wid >> 1, wn = wid & 1;
    const int m0 = blockIdx.y * 64, n0 = blockIdx.x * 64;
    const int z = blockIdx.z;
    X += (size_t)z * sXb;

    f32x4 acc[2][2] = {};

    const int arow = wid * 16 + (lane >> 2);
    const int als  = (lane & 3) ^ ((arow >> 1) & 3);
    const int lp = tid >> 4;          // l-pair 0..15
    const int d4 = (tid & 15) * 4;    // 0..60

    for (int k0 = 0; k0 < 2048; k0 += 32) {
        size_t gA = (size_t)(m0 + arow) * 2048 + k0 + als * 8;
        gll16(Ath + gA, &sA[0][wid * 512]);
        gll16(Atl + gA, &sA[1][wid * 512]);

        const float* xr = &X[(size_t)(k0 + 2 * lp) * 512 + n0 + d4];
        float4 v0 = *reinterpret_cast<const float4*>(xr);
        float4 v1 = *reinterpret_cast<const float4*>(xr + 512);
        float a0[4] = {v0.x, v0.y, v0.z, v0.w};
        float a1[4] = {v1.x, v1.y, v1.z, v1.w};
#pragma unroll
        for (int i = 0; i < 4; ++i) {
            unsigned short h0 = f2bf(a0[i]), h1 = f2bf(a1[i]);
            sB[0][(d4 + i) * 20 + lp] = (unsigned)h0 | ((unsigned)h1 << 16);
            unsigned short l0 = f2bf(a0[i] - bf2f(h0)), l1 = f2bf(a1[i] - bf2f(h1));
            sB[1][(d4 + i) * 20 + lp] = (unsigned)l0 | ((unsigned)l1 << 16);
        }
        __syncthreads();

        short8 a[2][2], b[2][2];
        const int s = lane >> 4;
#pragma unroll
        for (int i = 0; i < 2; ++i) {
            int r = wm * 32 + i * 16 + (lane & 15);
            int off = r * 32 + (s ^ ((r >> 1) & 3)) * 8;
            a[0][i] = *reinterpret_cast<const short8*>(&sA[0][off]);
            a[1][i] = *reinterpret_cast<const short8*>(&sA[1][off]);
        }
#pragma unroll
        for (int j = 0; j < 2; ++j) {
            int d = wn * 32 + j * 16 + (lane & 15);
            b[0][j] = *reinterpret_cast<const short8*>(&sB[0][d * 20 + s * 4]);
            b[1][j] = *reinterpret_cast<const short8*>(&sB[1][d * 20 + s * 4]);
        }
#pragma unroll
        for (int i = 0; i < 2; ++i)
#pragma unroll
            for (int j = 0; j < 2; ++j) {
                acc[i][j] = __builtin_amdgcn_mfma_f32_16x16x32_bf16(a[0][i], b[0][j], acc[i][j], 0, 0, 0);
                acc[i][j] = __builtin_amdgcn_mfma_f32_16x16x32_bf16(a[0][i], b[1][j], acc[i][j], 0, 0, 0);
                acc[i][j] = __builtin_amdgcn_mfma_f32_16x16x32_bf16(a[1][i], b[0][j], acc[i][j], 0, 0, 0);
            }
        __syncthreads();
    }

    const int cr = (lane >> 4) * 4, cc = lane & 15;
#pragma unroll
    for (int i = 0; i < 2; ++i)
#pragma unroll
        for (int j = 0; j < 2; ++j)
#pragma unroll
            for (int r = 0; r < 4; ++r) {
                int m = m0 + wm * 32 + i * 16 + cr + r;
                int n = n0 + wn * 32 + j * 16 + cc;
                size_t idx = (size_t)z * sOb + (size_t)m * 512 + n;
                float v = acc[i][j][r];
                unsigned short h = f2bf(v);
                Oh[idx] = h;
                Ol[idx] = f2bf(v - bf2f(h));
            }
}

// fp32 -> hi/lo bf16 planes, float4 path
__global__ __launch_bounds__(256)
void split_f32_kernel(const float* __restrict__ src, unsigned short* __restrict__ hi,
                      unsigned short* __restrict__ lo, int n4)
{
    int i = blockIdx.x * 256 + threadIdx.x;
    if (i >= n4) return;
    float4 v = reinterpret_cast<const float4*>(src)[i];
    ushort4 h, l;
    h.x = f2bf(v.x); l.x = f2bf(v.x - bf2f(h.x));
    h.y = f2bf(v.y); l.y = f2bf(v.y - bf2f(h.y));
    h.z = f2bf(v.z); l.z = f2bf(v.z - bf2f(h.z));
    h.w = f2bf(v.w); l.w = f2bf(v.w - bf2f(h.w));
    reinterpret_cast<ushort4*>(hi)[i] = h;
    reinterpret_cast<ushort4*>(lo)[i] = l;
}

// Tables as hi/lo planes: ft[t][l] (t<64 cos, t>=64 -sin of selected modes), it[l][t]
__global__ void build_tables_kernel(const int* __restrict__ midx,
                                    unsigned short* __restrict__ fth, unsigned short* __restrict__ ftl,
                                    unsigned short* __restrict__ ith, unsigned short* __restrict__ itl)
{
    const int l = blockIdx.x;
    const int t = threadIdx.x;
    const int m = t & 63;
    const bool im = t >= 64;
    const float c0 = 6.28318530717958647692f / 2048.0f;

    int f = midx[m];
    int ph = (f * l) & 2047;
    float s, c;
    sincosf(c0 * (float)ph, &s, &c);
    float v = im ? -s : c;
    unsigned short h = f2bf(v);
    fth[(size_t)t * 2048 + l] = h;
    ftl[(size_t)t * 2048 + l] = f2bf(v - bf2f(h));

    int ph2 = (m * l) & 2047;
    float s2, c2;
    sincosf(c0 * (float)ph2, &s2, &c2);
    float v2 = im ? s2 : c2;
    unsigned short h2 = f2bf(v2);
    ith[(size_t)l * 128 + t] = h2;
    itl[(size_t)l * 128 + t] = f2bf(v2 - bf2f(h2));
}

// Per (m,h): complex channel mix; writes scaled inverse coefficients as hi/lo planes.
__global__ __launch_bounds__(256)
void mode_mix_kernel(const float* __restrict__ xsel,
                     const float* __restrict__ wr, const float* __restrict__ wi,
                     unsigned short* __restrict__ cth, unsigned short* __restrict__ ctl)
{
    const int m = blockIdx.x;
    const int h = blockIdx.y;
    const int tid = threadIdx.x;

    __shared__ float xr[16][64], xi[16][64];
    __shared__ float wrs[64][65], wis[64][65];

    for (int i = tid; i < 4096; i += 256) {
        int e = i >> 6, o = i & 63;
        size_t g = (((size_t)h * 64 + e) * 64 + o) * 64 + m;
        wrs[e][o] = wr[g];
        wis[e][o] = wi[g];
    }
    for (int i = tid; i < 1024; i += 256) {
        int bb = i >> 6, e = i & 63;
        size_t g = ((size_t)bb * 512 + h * 64 + e) * 128;
        xr[bb][e] = xsel[g + m];
        xi[bb][e] = xsel[g + 64 + m];
    }
    __syncthreads();

    const int o = tid & 63;
    const int bq4 = tid >> 6;
    const float sc_r = (m == 0) ? (1.0f / 2048.0f) : (2.0f / 2048.0f);
    const float sc_i = (m == 0) ? 0.0f : (-2.0f / 2048.0f);

    for (int q = 0; q < 4; ++q) {
        int bb = bq4 * 4 + q;
        float or_ = 0.f, oi_ = 0.f;
#pragma unroll 16
        for (int e = 0; e < 64; ++e) {
            float xrv = xr[bb][e], xiv = xi[bb][e];
            float wrv = wrs[e][o], wiv = wis[e][o];
            or_ += xrv * wrv - xiv * wiv;
            oi_ += xrv * wiv + xiv * wrv;
        }
        size_t base = ((size_t)bb * 128 + m) * 512 + (size_t)h * 64 + o;
        float vr = or_ * sc_r;
        unsigned short hr = f2bf(vr);
        cth[base] = hr; ctl[base] = f2bf(vr - bf2f(hr));
        float vi = oi_ * sc_i;
        unsigned short hi2 = f2bf(vi);
        cth[base + 64 * 512] = hi2; ctl[base + 64 * 512] = f2bf(vi - bf2f(hi2));
    }
}

// decomp: R = X - sum_k softmax_k(X*w_k+b_k)*movavg_k(X). SPLIT: write hi/lo planes.
template<bool SPLIT>
__global__ __launch_bounds__(256)
void decomp_kernel(const float* __restrict__ X, float* __restrict__ Rf,
                   unsigned short* __restrict__ Rh, unsigned short* __restrict__ Rl,
                   const float* __restrict__ w, const float* __restrict__ bg)
{
    const int d = blockIdx.x * 256 + threadIdx.x;
    const int l0 = blockIdx.y * 64;
    const int b = blockIdx.z;
    const float w0 = w[0], w1 = w[1], b0 = bg[0], b1 = bg[1];

    const float* Xp = X + (size_t)b * 2048 * 512 + d;
    const size_t obase = (size_t)b * 2048 * 512 + d;

    float s1 = 0.f, s2 = 0.f;
    for (int i = l0 - 12; i <= l0 + 12; ++i) {
        int ic = min(max(i, 0), 2047);
        float v = Xp[(size_t)ic * 512];
        s2 += v;
        if (i >= l0 - 6 && i <= l0 + 6) s1 += v;
    }
    for (int l = l0; l < l0 + 64; ++l) {
        float xv = Xp[(size_t)l * 512];
        float m1 = s1 * (1.0f / 13.0f);
        float m2 = s2 * (1.0f / 25.0f);
        float e0 = xv * w0 + b0, e1 = xv * w1 + b1;
        float mx = fmaxf(e0, e1);
        float g0 = expf(e0 - mx), g1 = expf(e1 - mx);
        float mean = (g0 * m1 + g1 * m2) / (g0 + g1);
        float rv = xv - mean;
        size_t oi = obase + (size_t)l * 512;
        if (SPLIT) {
            unsigned short h = f2bf(rv);
            Rh[oi] = h;
            Rl[oi] = f2bf(rv - bf2f(h));
        } else {
            Rf[oi] = rv;
        }
        s1 += Xp[(size_t)min(l + 7, 2047) * 512] - Xp[(size_t)max(l - 6, 0) * 512];
        s2 += Xp[(size_t)min(l + 13, 2047) * 512] - Xp[(size_t)max(l - 12, 0) * 512];
    }
}

extern "C" void kernel_launch(void* const* d_in, const int* in_sizes, int n_in,
                              void* d_out, int out_size, void* d_ws, size_t ws_size,
                              hipStream_t stream)
{
    const float* x    = (const float*)d_in[0];
    const float* Wq   = (const float*)d_in[1];
    const float* bq   = (const float*)d_in[2];
    const float* Wo   = (const float*)d_in[7];
    const float* bo   = (const float*)d_in[8];
    const float* fwr  = (const float*)d_in[9];
    const float* fwi  = (const float*)d_in[10];
    const float* c1w  = (const float*)d_in[11];
    const float* c2w  = (const float*)d_in[12];
    const float* d1w  = (const float*)d_in[13];
    const float* d1b  = (const float*)d_in[14];
    const float* d2w  = (const float*)d_in[15];
    const float* d2b  = (const float*)d_in[16];
    const int*   midx = (const int*)d_in[17];
    float* out = (float*)d_out;
    float* ws  = (float*)d_ws;

    // ws layout (max 88MB, proven):
    //  [0   : 64MB)  region0: u (phase1) -> v (FFN out)
    //  [64MB: 84MB)  phase-1 planes+xsel (dead after K6); later re-used:
    //                [64:72MB) c1/c2 planes (split after K6), [72:88MB) h plane
    float* region0 = ws;
    unsigned short* p1 = (unsigned short*)(ws + 16777216);   // 64MB
    unsigned short* fth = p1;                    // 128x2048
    unsigned short* ftl = p1 + 262144;
    unsigned short* ith = p1 + 2 * 262144;       // 2048x128
    unsigned short* itl = p1 + 3 * 262144;
    unsigned short* wqh = p1 + 4 * 262144;       // 512x512
    unsigned short* wql = p1 + 5 * 262144;
    unsigned short* woh = p1 + 6 * 262144;
    unsigned short* wol = p1 + 7 * 262144;
    unsigned short* xfh = p1 + 2097152;          // 16x128x512
    unsigned short* xfl = p1 + 3145728;
    unsigned short* cth = p1 + 4194304;
    unsigned short* ctl = p1 + 5242880;
    unsigned short* zth = p1 + 6291456;
    unsigned short* ztl = p1 + 7340288;
    float* xsel = (float*)(p1 + 8388608);        // 80MB..84MB, fp32 16x512x128

    // FFN-time (phase-1 planes dead):
    unsigned short* c1h = p1;                    // 64MB..72MB
    unsigned short* c1l = p1 + 1048576;
    unsigned short* c2h = p1 + 2 * 1048576;
    unsigned short* c2l = p1 + 3 * 1048576;
    unsigned short* hh  = (unsigned short*)(ws + 18874368);  // 72MB, R*2048*2B = 16MB
    const int R = 4096;

    // r1 hi/lo planes live in d_out until K8 (d_out fully rewritten by K8)
    unsigned short* r1h = (unsigned short*)d_out;
    unsigned short* r1l = r1h + 16777216;

    const long long sBL = (long long)2048 * 512;
    const long long sP  = 65536;

    // T: tables + weight splits
    build_tables_kernel<<<2048, 128, 0, stream>>>(midx, fth, ftl, ith, itl);
    split_f32_kernel<<<256, 256, 0, stream>>>(Wq, wqh, wql, 65536);
    split_f32_kernel<<<256, 256, 0, stream>>>(Wo, woh, wol, 65536);

    // K1: xf planes
    gemm_dft<<<dim3(8, 2, 16), 256, 0, stream>>>(fth, ftl, x, sBL, xfh, xfl, sP);

    // K2: xsel = Wq @ xf^T (+ bq*L on f==0 real modes)
    gemm_hl<64, 64, EPI_WQFOLD, true, true><<<dim3(2, 8, 16), 256, 0, stream>>>(
        wqh, wql, 0, xfh, xfl, sP, xsel, nullptr, nullptr, sP,
        nullptr, nullptr, nullptr, 0, bq, midx, 128, 512);

    // K3: mode mixing -> coef planes
    mode_mix_kernel<<<dim3(64, 8), 256, 0, stream>>>(xsel, fwr, fwi, cth, ctl);

    // K4: zc planes = Wo @ coef^T
    gemm_hl<64, 64, EPI_SPLIT, true, true><<<dim3(2, 8, 16), 256, 0, stream>>>(
        woh, wol, 0, cth, ctl, sP, nullptr, zth, ztl, sP,
        nullptr, nullptr, nullptr, 0, nullptr, nullptr, 128, 512);

    // K5: u = x + bo + it @ zc^T
    gemm_hl<128, 64, EPI_INVU, true, true><<<dim3(8, 16, 16), 256, 0, stream>>>(
        ith, itl, 0, zth, ztl, sP, region0, nullptr, nullptr, sBL,
        nullptr, nullptr, x, sBL, bo, nullptr, 512, 128);

    // K6: r1 = decomp(u) -> hi/lo planes in d_out
    decomp_kernel<true><<<dim3(2, 32, 16), 256, 0, stream>>>(
        region0, nullptr, r1h, r1l, d1w, d1b);

    // FFN weight planes (phase-1 scratch now dead)
    split_f32_kernel<<<1024, 256, 0, stream>>>(c1w, c1h, c1l, 262144);
    split_f32_kernel<<<1024, 256, 0, stream>>>(c2w, c2h, c2l, 262144);

    // FFN chunks; u dead -> region0 receives v
    const int nc = 32768 / R;
    for (int c = 0; c < nc; ++c) {
        const unsigned short* r1hc = r1h + (size_t)c * R * 512;
        const unsigned short* r1lc = r1l + (size_t)c * R * 512;
        gemm_hl<128, 128, EPI_GELU, true, true><<<dim3(16, R / 128), 256, 0, stream>>>(
            r1hc, r1lc, 0, c1h, c1l, 0, nullptr, hh, nullptr, 0,
            nullptr, nullptr, nullptr, 0, nullptr, nullptr, 2048, 512);
        gemm_hl<128, 64, EPI_RES, false, true><<<dim3(8, R / 128), 256, 0, stream>>>(
            hh, nullptr, 0, c2h, c2l, 0, region0 + (size_t)c * R * 512, nullptr, nullptr, 0,
            r1hc, r1lc, nullptr, 0, nullptr, nullptr, 512, 2048);
    }

    // K8: out = decomp(v)
    decomp_kernel<false><<<dim3(2, 32, 16), 256, 0, stream>>>(
        region0, out, nullptr, nullptr, d2w, d2b);
}

// Round 6
// 840.292 us; speedup vs baseline: 3.9606x; 1.3305x over previous
//
#include <hip/hip_runtime.h>
#include <math.h>

// FEDformer encoder layer, MI355X. B=16, L=2048, D=512, H=8, E=64, M=64, DFF=2048.
// Round 5: gemm_dft split-K x4 (+LDS write-conflict fix); all gemm_hl GEMMs at
// 8 waves/block for 2x wave-level latency hiding. Everything else as round 4.

#define EPI_GELU   1
#define EPI_RES    2
#define EPI_SPLIT  3
#define EPI_WQFOLD 4
#define EPI_INVU   5

typedef __attribute__((ext_vector_type(8))) short short8;
typedef __attribute__((ext_vector_type(4))) float f32x4;

#define AS1 __attribute__((address_space(1)))
#define AS3 __attribute__((address_space(3)))

__device__ __forceinline__ void gll16(const void* g, void* l) {
    __builtin_amdgcn_global_load_lds((const AS1 void*)g, (AS3 void*)l, 16, 0, 0);
}

__device__ __forceinline__ float gelu_exact(float v) {
    return 0.5f * v * (1.0f + erff(v * 0.70710678118654752f));
}

__device__ __forceinline__ unsigned short f2bf(float f) {
    unsigned u = __builtin_bit_cast(unsigned, f);
    unsigned r = (u + 0x7fffu + ((u >> 16) & 1u)) >> 16;
    return (unsigned short)r;
}
__device__ __forceinline__ float bf2f(unsigned short h) {
    unsigned u = ((unsigned)h) << 16;
    return __builtin_bit_cast(float, u);
}

// ---------------- generalized split-bf16 MFMA GEMM (8 waves) ----------------
// C[m,n] = sum_k A(m,k)*B(n,k); A,B bf16 plane pairs (k-contig rows, stride K).
// BM x BN tile, BK=32, 8 waves (2m x 4n), wave tile (BM/2) x (BN/4).
// LDS chunk = 16 rows x 32 k = 1KB, one gll16 per chunk; logical 16B slot =
// physical ^ ((row>>1)&3) applied on the global source address.
template<int BM, int BN, int EPI, bool ALO, bool BLO>
__global__ __launch_bounds__(512)
void gemm_hl(const unsigned short* __restrict__ Ah, const unsigned short* __restrict__ Al, long long sAb,
             const unsigned short* __restrict__ Bh, const unsigned short* __restrict__ Bl, long long sBb,
             float* __restrict__ Cf, unsigned short* __restrict__ Ch, unsigned short* __restrict__ Cl,
             long long sCb,
             const unsigned short* __restrict__ Rh, const unsigned short* __restrict__ Rl,
             const float* __restrict__ resf, long long sRb,
             const float* __restrict__ bias, const int* __restrict__ midx,
             int N, int K)
{
    constexpr int MI = BM / 32, NJ = BN / 64;   // frags per wave: (BM/2)/16 x (BN/4)/16
    __shared__ __align__(16) unsigned short sA[ALO ? 2 : 1][BM * 32];
    __shared__ __align__(16) unsigned short sB[BLO ? 2 : 1][BN * 32];

    const int tid = threadIdx.x, lane = tid & 63, wid = tid >> 6;
    const int wm = wid >> 2, wn = wid & 3;
    const int m0 = blockIdx.y * BM, n0 = blockIdx.x * BN;
    const int z = blockIdx.z;

    Ah += (size_t)z * sAb; if (ALO) Al += (size_t)z * sAb;
    Bh += (size_t)z * sBb; if (BLO) Bl += (size_t)z * sBb;

    f32x4 acc[MI][NJ] = {};

    const int srr = lane >> 2;   // row within 16-row chunk
    const int sp  = lane & 3;    // physical 16B slot

    for (int k0 = 0; k0 < K; k0 += 32) {
        for (int ch = wid; ch < BM / 16; ch += 8) {
            int row = ch * 16 + srr;
            int ls = sp ^ ((row >> 1) & 3);
            size_t g = (size_t)(m0 + row) * K + k0 + ls * 8;
            gll16(Ah + g, &sA[0][ch * 512]);
            if (ALO) gll16(Al + g, &sA[1][ch * 512]);
        }
        for (int ch = wid; ch < BN / 16; ch += 8) {
            int row = ch * 16 + srr;
            int ls = sp ^ ((row >> 1) & 3);
            size_t g = (size_t)(n0 + row) * K + k0 + ls * 8;
            gll16(Bh + g, &sB[0][ch * 512]);
            if (BLO) gll16(Bl + g, &sB[1][ch * 512]);
        }
        __syncthreads();

        short8 a[ALO ? 2 : 1][MI], b[BLO ? 2 : 1][NJ];
        const int s = lane >> 4;
#pragma unroll
        for (int i = 0; i < MI; ++i) {
            int r = wm * (BM / 2) + i * 16 + (lane & 15);
            int off = r * 32 + (s ^ ((r >> 1) & 3)) * 8;
            a[0][i] = *reinterpret_cast<const short8*>(&sA[0][off]);
            if (ALO) a[1][i] = *reinterpret_cast<const short8*>(&sA[1][off]);
        }
#pragma unroll
        for (int j = 0; j < NJ; ++j) {
            int r = wn * (BN / 4) + j * 16 + (lane & 15);
            int off = r * 32 + (s ^ ((r >> 1) & 3)) * 8;
            b[0][j] = *reinterpret_cast<const short8*>(&sB[0][off]);
            if (BLO) b[1][j] = *reinterpret_cast<const short8*>(&sB[1][off]);
        }
#pragma unroll
        for (int i = 0; i < MI; ++i)
#pragma unroll
            for (int j = 0; j < NJ; ++j) {
                acc[i][j] = __builtin_amdgcn_mfma_f32_16x16x32_bf16(a[0][i], b[0][j], acc[i][j], 0, 0, 0);
                if (BLO)
                    acc[i][j] = __builtin_amdgcn_mfma_f32_16x16x32_bf16(a[0][i], b[1][j], acc[i][j], 0, 0, 0);
                if (ALO)
                    acc[i][j] = __builtin_amdgcn_mfma_f32_16x16x32_bf16(a[1][i], b[0][j], acc[i][j], 0, 0, 0);
            }
        __syncthreads();
    }

    // C/D layout (m89-verified): col = lane&15, row = (lane>>4)*4 + reg
    const int cr = (lane >> 4) * 4, cc = lane & 15;
#pragma unroll
    for (int i = 0; i < MI; ++i)
#pragma unroll
        for (int j = 0; j < NJ; ++j)
#pragma unroll
            for (int r = 0; r < 4; ++r) {
                int m = m0 + wm * (BM / 2) + i * 16 + cr + r;
                int n = n0 + wn * (BN / 4) + j * 16 + cc;
                size_t idx = (size_t)z * sCb + (size_t)m * N + n;
                float v = acc[i][j][r];
                if (EPI == EPI_GELU) {
                    Ch[idx] = f2bf(gelu_exact(v));
                } else if (EPI == EPI_RES) {
                    size_t ri = (size_t)m * N + n;
                    Cf[idx] = v + bf2f(Rh[ri]) + bf2f(Rl[ri]);
                } else if (EPI == EPI_SPLIT) {
                    unsigned short h = f2bf(v);
                    Ch[idx] = h;
                    Cl[idx] = f2bf(v - bf2f(h));
                } else if (EPI == EPI_WQFOLD) {
                    if (n < 64 && midx[n] == 0) v += bias[m] * 2048.0f;
                    Cf[idx] = v;
                } else if (EPI == EPI_INVU) {
                    size_t ri = (size_t)z * sRb + (size_t)m * N + n;
                    Cf[idx] = v + resf[ri] + bias[n];
                }
            }
}

// ---------------- K1: forward DFT GEMM, split-K x4 ----------------
// partial[z][t][d] = sum_{l in slice} ft[t][l] * x[l][d],  z = b*4 + ks.
// A = ft planes (k-contig, gll16).  B = x fp32 [l][d]: reg-staged, transposed+split
// into LDS [d][l-pairs u32] pitch 20; physical slot = lp ^ (((d>>3)&3)<<2)
// (2-way write conflicts; b128 reads stay 16B-contiguous).
__global__ __launch_bounds__(256)
void gemm_dft(const unsigned short* __restrict__ Ath, const unsigned short* __restrict__ Atl,
              const float* __restrict__ X, long long sXb,
              float* __restrict__ P)
{
    __shared__ __align__(16) unsigned short sA[2][64 * 32];
    __shared__ __align__(16) unsigned sB[2][64 * 20];

    const int tid = threadIdx.x, lane = tid & 63, wid = tid >> 6;
    const int wm = wid >> 1, wn = wid & 1;
    const int m0 = blockIdx.y * 64, n0 = blockIdx.x * 64;
    const int z = blockIdx.z;           // b*4 + ks
    const int b = z >> 2, ks = z & 3;
    X += (size_t)b * sXb;

    f32x4 acc[2][2] = {};

    const int arow = wid * 16 + (lane >> 2);
    const int als  = (lane & 3) ^ ((arow >> 1) & 3);
    const int lp = tid >> 4;          // l-pair 0..15
    const int d4 = (tid & 15) * 4;    // 0..60

    for (int kk = 0; kk < 512; kk += 32) {
        const int k0 = ks * 512 + kk;
        size_t gA = (size_t)(m0 + arow) * 2048 + k0 + als * 8;
        gll16(Ath + gA, &sA[0][wid * 512]);
        gll16(Atl + gA, &sA[1][wid * 512]);

        const float* xr = &X[(size_t)(k0 + 2 * lp) * 512 + n0 + d4];
        float4 v0 = *reinterpret_cast<const float4*>(xr);
        float4 v1 = *reinterpret_cast<const float4*>(xr + 512);
        float a0[4] = {v0.x, v0.y, v0.z, v0.w};
        float a1[4] = {v1.x, v1.y, v1.z, v1.w};
#pragma unroll
        for (int i = 0; i < 4; ++i) {
            int row = d4 + i;
            int slot = lp ^ (((row >> 3) & 3) << 2);
            unsigned short h0 = f2bf(a0[i]), h1 = f2bf(a1[i]);
            sB[0][row * 20 + slot] = (unsigned)h0 | ((unsigned)h1 << 16);
            unsigned short l0 = f2bf(a0[i] - bf2f(h0)), l1 = f2bf(a1[i] - bf2f(h1));
            sB[1][row * 20 + slot] = (unsigned)l0 | ((unsigned)l1 << 16);
        }
        __syncthreads();

        short8 a[2][2], b2[2][2];
        const int s = lane >> 4;
#pragma unroll
        for (int i = 0; i < 2; ++i) {
            int r = wm * 32 + i * 16 + (lane & 15);
            int off = r * 32 + (s ^ ((r >> 1) & 3)) * 8;
            a[0][i] = *reinterpret_cast<const short8*>(&sA[0][off]);
            a[1][i] = *reinterpret_cast<const short8*>(&sA[1][off]);
        }
#pragma unroll
        for (int j = 0; j < 2; ++j) {
            int d = wn * 32 + j * 16 + (lane & 15);
            int off = d * 20 + ((s * 4) ^ (((d >> 3) & 3) << 2));
            b2[0][j] = *reinterpret_cast<const short8*>(&sB[0][off]);
            b2[1][j] = *reinterpret_cast<const short8*>(&sB[1][off]);
        }
#pragma unroll
        for (int i = 0; i < 2; ++i)
#pragma unroll
            for (int j = 0; j < 2; ++j) {
                acc[i][j] = __builtin_amdgcn_mfma_f32_16x16x32_bf16(a[0][i], b2[0][j], acc[i][j], 0, 0, 0);
                acc[i][j] = __builtin_amdgcn_mfma_f32_16x16x32_bf16(a[0][i], b2[1][j], acc[i][j], 0, 0, 0);
                acc[i][j] = __builtin_amdgcn_mfma_f32_16x16x32_bf16(a[1][i], b2[0][j], acc[i][j], 0, 0, 0);
            }
        __syncthreads();
    }

    const int cr = (lane >> 4) * 4, cc = lane & 15;
#pragma unroll
    for (int i = 0; i < 2; ++i)
#pragma unroll
        for (int j = 0; j < 2; ++j)
#pragma unroll
            for (int r = 0; r < 4; ++r) {
                int m = m0 + wm * 32 + i * 16 + cr + r;
                int n = n0 + wn * 32 + j * 16 + cc;
                P[((size_t)z * 128 + m) * 512 + n] = acc[i][j][r];
            }
}

// sum 4 K-slices -> xf hi/lo planes
__global__ __launch_bounds__(256)
void dft_reduce(const float* __restrict__ P, unsigned short* __restrict__ Oh,
                unsigned short* __restrict__ Ol)
{
    int i = blockIdx.x * 256 + threadIdx.x;     // 16*128*128 float4s
    int b = i >> 14;
    int r = i & 16383;
    const float4* p = reinterpret_cast<const float4*>(P) + ((size_t)b * 4) * 16384 + r;
    float4 v = p[0];
    float4 v1 = p[16384], v2 = p[2 * 16384], v3 = p[3 * 16384];
    v.x += v1.x + v2.x + v3.x;
    v.y += v1.y + v2.y + v3.y;
    v.z += v1.z + v2.z + v3.z;
    v.w += v1.w + v2.w + v3.w;
    ushort4 h, l;
    h.x = f2bf(v.x); l.x = f2bf(v.x - bf2f(h.x));
    h.y = f2bf(v.y); l.y = f2bf(v.y - bf2f(h.y));
    h.z = f2bf(v.z); l.z = f2bf(v.z - bf2f(h.z));
    h.w = f2bf(v.w); l.w = f2bf(v.w - bf2f(h.w));
    size_t o = (size_t)b * 16384 + r;
    reinterpret_cast<ushort4*>(Oh)[o] = h;
    reinterpret_cast<ushort4*>(Ol)[o] = l;
}

// fp32 -> hi/lo bf16 planes, float4 path
__global__ __launch_bounds__(256)
void split_f32_kernel(const float* __restrict__ src, unsigned short* __restrict__ hi,
                      unsigned short* __restrict__ lo, int n4)
{
    int i = blockIdx.x * 256 + threadIdx.x;
    if (i >= n4) return;
    float4 v = reinterpret_cast<const float4*>(src)[i];
    ushort4 h, l;
    h.x = f2bf(v.x); l.x = f2bf(v.x - bf2f(h.x));
    h.y = f2bf(v.y); l.y = f2bf(v.y - bf2f(h.y));
    h.z = f2bf(v.z); l.z = f2bf(v.z - bf2f(h.z));
    h.w = f2bf(v.w); l.w = f2bf(v.w - bf2f(h.w));
    reinterpret_cast<ushort4*>(hi)[i] = h;
    reinterpret_cast<ushort4*>(lo)[i] = l;
}

// Tables as hi/lo planes: ft[t][l] (t<64 cos, t>=64 -sin of selected modes), it[l][t]
__global__ void build_tables_kernel(const int* __restrict__ midx,
                                    unsigned short* __restrict__ fth, unsigned short* __restrict__ ftl,
                                    unsigned short* __restrict__ ith, unsigned short* __restrict__ itl)
{
    const int l = blockIdx.x;
    const int t = threadIdx.x;
    const int m = t & 63;
    const bool im = t >= 64;
    const float c0 = 6.28318530717958647692f / 2048.0f;

    int f = midx[m];
    int ph = (f * l) & 2047;
    float s, c;
    sincosf(c0 * (float)ph, &s, &c);
    float v = im ? -s : c;
    unsigned short h = f2bf(v);
    fth[(size_t)t * 2048 + l] = h;
    ftl[(size_t)t * 2048 + l] = f2bf(v - bf2f(h));

    int ph2 = (m * l) & 2047;
    float s2, c2;
    sincosf(c0 * (float)ph2, &s2, &c2);
    float v2 = im ? s2 : c2;
    unsigned short h2 = f2bf(v2);
    ith[(size_t)l * 128 + t] = h2;
    itl[(size_t)l * 128 + t] = f2bf(v2 - bf2f(h2));
}

// Per (m,h): complex channel mix; writes scaled inverse coefficients as hi/lo planes.
__global__ __launch_bounds__(256)
void mode_mix_kernel(const float* __restrict__ xsel,
                     const float* __restrict__ wr, const float* __restrict__ wi,
                     unsigned short* __restrict__ cth, unsigned short* __restrict__ ctl)
{
    const int m = blockIdx.x;
    const int h = blockIdx.y;
    const int tid = threadIdx.x;

    __shared__ float xr[16][64], xi[16][64];
    __shared__ float wrs[64][65], wis[64][65];

    for (int i = tid; i < 4096; i += 256) {
        int e = i >> 6, o = i & 63;
        size_t g = (((size_t)h * 64 + e) * 64 + o) * 64 + m;
        wrs[e][o] = wr[g];
        wis[e][o] = wi[g];
    }
    for (int i = tid; i < 1024; i += 256) {
        int bb = i >> 6, e = i & 63;
        size_t g = ((size_t)bb * 512 + h * 64 + e) * 128;
        xr[bb][e] = xsel[g + m];
        xi[bb][e] = xsel[g + 64 + m];
    }
    __syncthreads();

    const int o = tid & 63;
    const int bq4 = tid >> 6;
    const float sc_r = (m == 0) ? (1.0f / 2048.0f) : (2.0f / 2048.0f);
    const float sc_i = (m == 0) ? 0.0f : (-2.0f / 2048.0f);

    for (int q = 0; q < 4; ++q) {
        int bb = bq4 * 4 + q;
        float or_ = 0.f, oi_ = 0.f;
#pragma unroll 16
        for (int e = 0; e < 64; ++e) {
            float xrv = xr[bb][e], xiv = xi[bb][e];
            float wrv = wrs[e][o], wiv = wis[e][o];
            or_ += xrv * wrv - xiv * wiv;
            oi_ += xrv * wiv + xiv * wrv;
        }
        size_t base = ((size_t)bb * 128 + m) * 512 + (size_t)h * 64 + o;
        float vr = or_ * sc_r;
        unsigned short hr = f2bf(vr);
        cth[base] = hr; ctl[base] = f2bf(vr - bf2f(hr));
        float vi = oi_ * sc_i;
        unsigned short hi2 = f2bf(vi);
        cth[base + 64 * 512] = hi2; ctl[base + 64 * 512] = f2bf(vi - bf2f(hi2));
    }
}

// decomp: R = X - sum_k softmax_k(X*w_k+b_k)*movavg_k(X). SPLIT: write hi/lo planes.
template<bool SPLIT>
__global__ __launch_bounds__(256)
void decomp_kernel(const float* __restrict__ X, float* __restrict__ Rf,
                   unsigned short* __restrict__ Rh, unsigned short* __restrict__ Rl,
                   const float* __restrict__ w, const float* __restrict__ bg)
{
    const int d = blockIdx.x * 256 + threadIdx.x;
    const int l0 = blockIdx.y * 64;
    const int b = blockIdx.z;
    const float w0 = w[0], w1 = w[1], b0 = bg[0], b1 = bg[1];

    const float* Xp = X + (size_t)b * 2048 * 512 + d;
    const size_t obase = (size_t)b * 2048 * 512 + d;

    float s1 = 0.f, s2 = 0.f;
    for (int i = l0 - 12; i <= l0 + 12; ++i) {
        int ic = min(max(i, 0), 2047);
        float v = Xp[(size_t)ic * 512];
        s2 += v;
        if (i >= l0 - 6 && i <= l0 + 6) s1 += v;
    }
    for (int l = l0; l < l0 + 64; ++l) {
        float xv = Xp[(size_t)l * 512];
        float m1 = s1 * (1.0f / 13.0f);
        float m2 = s2 * (1.0f / 25.0f);
        float e0 = xv * w0 + b0, e1 = xv * w1 + b1;
        float mx = fmaxf(e0, e1);
        float g0 = expf(e0 - mx), g1 = expf(e1 - mx);
        float mean = (g0 * m1 + g1 * m2) / (g0 + g1);
        float rv = xv - mean;
        size_t oi = obase + (size_t)l * 512;
        if (SPLIT) {
            unsigned short h = f2bf(rv);
            Rh[oi] = h;
            Rl[oi] = f2bf(rv - bf2f(h));
        } else {
            Rf[oi] = rv;
        }
        s1 += Xp[(size_t)min(l + 7, 2047) * 512] - Xp[(size_t)max(l - 6, 0) * 512];
        s2 += Xp[(size_t)min(l + 13, 2047) * 512] - Xp[(size_t)max(l - 12, 0) * 512];
    }
}

extern "C" void kernel_launch(void* const* d_in, const int* in_sizes, int n_in,
                              void* d_out, int out_size, void* d_ws, size_t ws_size,
                              hipStream_t stream)
{
    const float* x    = (const float*)d_in[0];
    const float* Wq   = (const float*)d_in[1];
    const float* bq   = (const float*)d_in[2];
    const float* Wo   = (const float*)d_in[7];
    const float* bo   = (const float*)d_in[8];
    const float* fwr  = (const float*)d_in[9];
    const float* fwi  = (const float*)d_in[10];
    const float* c1w  = (const float*)d_in[11];
    const float* c2w  = (const float*)d_in[12];
    const float* d1w  = (const float*)d_in[13];
    const float* d1b  = (const float*)d_in[14];
    const float* d2w  = (const float*)d_in[15];
    const float* d2b  = (const float*)d_in[16];
    const int*   midx = (const int*)d_in[17];
    float* out = (float*)d_out;
    float* ws  = (float*)d_ws;

    // ws layout:
    //  [0   : 64MB)  region0: K1 partials (16MB) -> u (phase1) -> v (FFN out)
    //  [64MB: 84MB)  phase-1 planes+xsel (dead after K6); re-used at FFN time:
    //                [64:72MB) c1/c2 planes, [72MB: ) h bf16 plane (R*2048*2B)
    float* region0 = ws;
    unsigned short* p1 = (unsigned short*)(ws + 16777216);   // 64MB
    unsigned short* fth = p1;                    // 128x2048
    unsigned short* ftl = p1 + 262144;
    unsigned short* ith = p1 + 2 * 262144;       // 2048x128
    unsigned short* itl = p1 + 3 * 262144;
    unsigned short* wqh = p1 + 4 * 262144;       // 512x512
    unsigned short* wql = p1 + 5 * 262144;
    unsigned short* woh = p1 + 6 * 262144;
    unsigned short* wol = p1 + 7 * 262144;
    unsigned short* xfh = p1 + 2097152;          // 16x128x512
    unsigned short* xfl = p1 + 3145728;
    unsigned short* cth = p1 + 4194304;
    unsigned short* ctl = p1 + 5242880;
    unsigned short* zth = p1 + 6291456;
    unsigned short* ztl = p1 + 7340288;
    float* xsel = (float*)(p1 + 8388608);        // 80MB..84MB, fp32 16x512x128

    // FFN-time (phase-1 planes dead):
    unsigned short* c1h = p1;                    // 64MB..72MB
    unsigned short* c1l = p1 + 1048576;
    unsigned short* c2h = p1 + 2 * 1048576;
    unsigned short* c2l = p1 + 3 * 1048576;
    unsigned short* hh  = (unsigned short*)(ws + 18874368);  // 72MB
    // adaptive FFN chunk rows: h plane = R*2048*2B at 72MB
    const size_t hbase = 72ull << 20;
    const int R = (ws_size >= hbase + (size_t)8192 * 2048 * 2) ? 8192 : 4096;

    // r1 hi/lo planes live in d_out until K8 (d_out fully rewritten by K8)
    unsigned short* r1h = (unsigned short*)d_out;
    unsigned short* r1l = r1h + 16777216;

    const long long sBL = (long long)2048 * 512;
    const long long sP  = 65536;

    // T: tables + weight splits
    build_tables_kernel<<<2048, 128, 0, stream>>>(midx, fth, ftl, ith, itl);
    split_f32_kernel<<<256, 256, 0, stream>>>(Wq, wqh, wql, 65536);
    split_f32_kernel<<<256, 256, 0, stream>>>(Wo, woh, wol, 65536);

    // K1: split-K x4 partials into region0, then reduce -> xf planes
    gemm_dft<<<dim3(8, 2, 64), 256, 0, stream>>>(fth, ftl, x, sBL, region0);
    dft_reduce<<<1024, 256, 0, stream>>>(region0, xfh, xfl);

    // K2: xsel = Wq @ xf^T (+ bq*L on f==0 real modes)
    gemm_hl<64, 64, EPI_WQFOLD, true, true><<<dim3(2, 8, 16), 512, 0, stream>>>(
        wqh, wql, 0, xfh, xfl, sP, xsel, nullptr, nullptr, sP,
        nullptr, nullptr, nullptr, 0, bq, midx, 128, 512);

    // K3: mode mixing -> coef planes
    mode_mix_kernel<<<dim3(64, 8), 256, 0, stream>>>(xsel, fwr, fwi, cth, ctl);

    // K4: zc planes = Wo @ coef^T
    gemm_hl<64, 64, EPI_SPLIT, true, true><<<dim3(2, 8, 16), 512, 0, stream>>>(
        woh, wol, 0, cth, ctl, sP, nullptr, zth, ztl, sP,
        nullptr, nullptr, nullptr, 0, nullptr, nullptr, 128, 512);

    // K5: u = x + bo + it @ zc^T
    gemm_hl<128, 64, EPI_INVU, true, true><<<dim3(8, 16, 16), 512, 0, stream>>>(
        ith, itl, 0, zth, ztl, sP, region0, nullptr, nullptr, sBL,
        nullptr, nullptr, x, sBL, bo, nullptr, 512, 128);

    // K6: r1 = decomp(u) -> hi/lo planes in d_out
    decomp_kernel<true><<<dim3(2, 32, 16), 256, 0, stream>>>(
        region0, nullptr, r1h, r1l, d1w, d1b);

    // FFN weight planes (phase-1 scratch now dead)
    split_f32_kernel<<<1024, 256, 0, stream>>>(c1w, c1h, c1l, 262144);
    split_f32_kernel<<<1024, 256, 0, stream>>>(c2w, c2h, c2l, 262144);

    // FFN chunks; u dead -> region0 receives v
    const int nc = 32768 / R;
    for (int c = 0; c < nc; ++c) {
        const unsigned short* r1hc = r1h + (size_t)c * R * 512;
        const unsigned short* r1lc = r1l + (size_t)c * R * 512;
        gemm_hl<128, 128, EPI_GELU, true, true><<<dim3(16, R / 128), 512, 0, stream>>>(
            r1hc, r1lc, 0, c1h, c1l, 0, nullptr, hh, nullptr, 0,
            nullptr, nullptr, nullptr, 0, nullptr, nullptr, 2048, 512);
        gemm_hl<128, 64, EPI_RES, false, true><<<dim3(8, R / 128), 512, 0, stream>>>(
            hh, nullptr, 0, c2h, c2l, 0, region0 + (size_t)c * R * 512, nullptr, nullptr, 0,
            r1hc, r1lc, nullptr, 0, nullptr, nullptr, 512, 2048);
    }

    // K8: out = decomp(v)
    decomp_kernel<false><<<dim3(2, 32, 16), 256, 0, stream>>>(
        region0, out, nullptr, nullptr, d2w, d2b);
}

// Round 7
// 674.301 us; speedup vs baseline: 4.9356x; 1.2462x over previous
//
#include <hip/hip_runtime.h>
#include <math.h>

// FEDformer encoder layer, MI355X. B=16, L=2048, D=512, H=8, E=64, M=64, DFF=2048.
// Round 6: single-plane bf16 MFMA everywhere (fp32 accum; r1 residual kept hi+lo).
// XCD-aware block swizzle on all gemm_hl grids. BN=128 for G2/K5.
//
//  T:  tables -> ft/it bf16; cvt Wq,Wo
//  K1 gemm_dft (split-K x4) + dft_reduce -> xf bf16
//  K2 gemm_hl<64,64,WQFOLD>: xsel = Wq @ xf^T (+bq*L on f==0)   -> fp32
//  K3 mode_mix -> coef bf16
//  K4 gemm_hl<64,64,BF16>:   zc = Wo @ coef^T                    -> bf16
//  K5 gemm_hl<128,128,INVU>: u = x + bo + it @ zc^T              -> fp32
//  K6 decomp(u) -> r1 hi/lo planes (d_out)
//  cvt c1,c2; per chunk (R=8192): G1 gelu GEMM -> h bf16; G2 res GEMM -> v fp32
//  K8 decomp(v) -> out

#define EPI_GELU   1
#define EPI_RES    2
#define EPI_BF16   3
#define EPI_WQFOLD 4
#define EPI_INVU   5

typedef __attribute__((ext_vector_type(8))) short short8;
typedef __attribute__((ext_vector_type(4))) float f32x4;

#define AS1 __attribute__((address_space(1)))
#define AS3 __attribute__((address_space(3)))

__device__ __forceinline__ void gll16(const void* g, void* l) {
    __builtin_amdgcn_global_load_lds((const AS1 void*)g, (AS3 void*)l, 16, 0, 0);
}

__device__ __forceinline__ float gelu_exact(float v) {
    return 0.5f * v * (1.0f + erff(v * 0.70710678118654752f));
}

__device__ __forceinline__ unsigned short f2bf(float f) {
    unsigned u = __builtin_bit_cast(unsigned, f);
    unsigned r = (u + 0x7fffu + ((u >> 16) & 1u)) >> 16;
    return (unsigned short)r;
}
__device__ __forceinline__ float bf2f(unsigned short h) {
    unsigned u = ((unsigned)h) << 16;
    return __builtin_bit_cast(float, u);
}

// ---------------- bf16 MFMA GEMM (8 waves, single-plane, fp32 acc) ----------------
// C[m,n] = sum_k A(m,k)*B(n,k); A,B bf16 (k-contig rows, stride K).
// BM x BN tile, BK=32, 8 waves (2m x 4n), wave tile (BM/2) x (BN/4).
// LDS chunk = 16 rows x 32 k = 1KB, one gll16; logical 16B slot =
// physical ^ ((row>>1)&3) applied on the global source address.
// XCD swizzle: bijective remap of flat block id when nwg % 8 == 0.
template<int BM, int BN, int EPI>
__global__ __launch_bounds__(512)
void gemm_hl(const unsigned short* __restrict__ Ah, long long sAb,
             const unsigned short* __restrict__ Bh, long long sBb,
             float* __restrict__ Cf, unsigned short* __restrict__ Ch, long long sCb,
             const unsigned short* __restrict__ Rh, const unsigned short* __restrict__ Rl,
             const float* __restrict__ resf, long long sRb,
             const float* __restrict__ bias, const int* __restrict__ midx,
             int N, int K)
{
    constexpr int MI = BM / 32, NJ = BN / 64;   // frags/wave: (BM/2)/16 x (BN/4)/16
    __shared__ __align__(16) unsigned short sA[BM * 32];
    __shared__ __align__(16) unsigned short sB[BN * 32];

    const int tid = threadIdx.x, lane = tid & 63, wid = tid >> 6;
    const int wm = wid >> 2, wn = wid & 3;

    // XCD-aware bijective swizzle of the (x,y) plane
    const int gx = gridDim.x;
    int flat = blockIdx.y * gx + blockIdx.x;
    const int nwg = gx * gridDim.y;
    if ((nwg & 7) == 0) {
        const int cpx = nwg >> 3;
        flat = (flat & 7) * cpx + (flat >> 3);
    }
    const int m0 = (flat / gx) * BM, n0 = (flat % gx) * BN;
    const int z = blockIdx.z;

    Ah += (size_t)z * sAb;
    Bh += (size_t)z * sBb;

    f32x4 acc[MI][NJ] = {};

    const int srr = lane >> 2;   // row within 16-row chunk
    const int sp  = lane & 3;    // physical 16B slot

    for (int k0 = 0; k0 < K; k0 += 32) {
        for (int ch = wid; ch < BM / 16; ch += 8) {
            int row = ch * 16 + srr;
            int ls = sp ^ ((row >> 1) & 3);
            gll16(Ah + (size_t)(m0 + row) * K + k0 + ls * 8, &sA[ch * 512]);
        }
        for (int ch = wid; ch < BN / 16; ch += 8) {
            int row = ch * 16 + srr;
            int ls = sp ^ ((row >> 1) & 3);
            gll16(Bh + (size_t)(n0 + row) * K + k0 + ls * 8, &sB[ch * 512]);
        }
        __syncthreads();

        short8 a[MI], b[NJ];
        const int s = lane >> 4;
#pragma unroll
        for (int i = 0; i < MI; ++i) {
            int r = wm * (BM / 2) + i * 16 + (lane & 15);
            a[i] = *reinterpret_cast<const short8*>(&sA[r * 32 + (s ^ ((r >> 1) & 3)) * 8]);
        }
#pragma unroll
        for (int j = 0; j < NJ; ++j) {
            int r = wn * (BN / 4) + j * 16 + (lane & 15);
            b[j] = *reinterpret_cast<const short8*>(&sB[r * 32 + (s ^ ((r >> 1) & 3)) * 8]);
        }
#pragma unroll
        for (int i = 0; i < MI; ++i)
#pragma unroll
            for (int j = 0; j < NJ; ++j)
                acc[i][j] = __builtin_amdgcn_mfma_f32_16x16x32_bf16(a[i], b[j], acc[i][j], 0, 0, 0);
        __syncthreads();
    }

    // C/D layout (m89-verified): col = lane&15, row = (lane>>4)*4 + reg
    const int cr = (lane >> 4) * 4, cc = lane & 15;
#pragma unroll
    for (int i = 0; i < MI; ++i)
#pragma unroll
        for (int j = 0; j < NJ; ++j)
#pragma unroll
            for (int r = 0; r < 4; ++r) {
                int m = m0 + wm * (BM / 2) + i * 16 + cr + r;
                int n = n0 + wn * (BN / 4) + j * 16 + cc;
                size_t idx = (size_t)z * sCb + (size_t)m * N + n;
                float v = acc[i][j][r];
                if (EPI == EPI_GELU) {
                    Ch[idx] = f2bf(gelu_exact(v));
                } else if (EPI == EPI_RES) {
                    size_t ri = (size_t)m * N + n;
                    Cf[idx] = v + bf2f(Rh[ri]) + bf2f(Rl[ri]);
                } else if (EPI == EPI_BF16) {
                    Ch[idx] = f2bf(v);
                } else if (EPI == EPI_WQFOLD) {
                    if (n < 64 && midx[n] == 0) v += bias[m] * 2048.0f;
                    Cf[idx] = v;
                } else if (EPI == EPI_INVU) {
                    size_t ri = (size_t)z * sRb + (size_t)m * N + n;
                    Cf[idx] = v + resf[ri] + bias[n];
                }
            }
}

// ---------------- K1: forward DFT GEMM, split-K x4, single-plane ----------------
// partial[z][t][d] = sum_{l in slice} ft[t][l] * x[l][d],  z = b*4 + ks.
// A = ft bf16 (k-contig, gll16). B = x fp32 [l][d]: reg-staged, transposed+cast
// into LDS [d][l-pairs u32] pitch 20; physical slot = lp ^ (((d>>3)&3)<<2).
__global__ __launch_bounds__(256)
void gemm_dft(const unsigned short* __restrict__ Ath,
              const float* __restrict__ X, long long sXb,
              float* __restrict__ P)
{
    __shared__ __align__(16) unsigned short sA[64 * 32];
    __shared__ __align__(16) unsigned sB[64 * 20];

    const int tid = threadIdx.x, lane = tid & 63, wid = tid >> 6;
    const int wm = wid >> 1, wn = wid & 1;
    const int m0 = blockIdx.y * 64, n0 = blockIdx.x * 64;
    const int z = blockIdx.z;           // b*4 + ks
    const int b = z >> 2, ks = z & 3;
    X += (size_t)b * sXb;

    f32x4 acc[2][2] = {};

    const int arow = wid * 16 + (lane >> 2);
    const int als  = (lane & 3) ^ ((arow >> 1) & 3);
    const int lp = tid >> 4;          // l-pair 0..15
    const int d4 = (tid & 15) * 4;    // 0..60

    for (int kk = 0; kk < 512; kk += 32) {
        const int k0 = ks * 512 + kk;
        gll16(Ath + (size_t)(m0 + arow) * 2048 + k0 + als * 8, &sA[wid * 512]);

        const float* xr = &X[(size_t)(k0 + 2 * lp) * 512 + n0 + d4];
        float4 v0 = *reinterpret_cast<const float4*>(xr);
        float4 v1 = *reinterpret_cast<const float4*>(xr + 512);
        float a0[4] = {v0.x, v0.y, v0.z, v0.w};
        float a1[4] = {v1.x, v1.y, v1.z, v1.w};
#pragma unroll
        for (int i = 0; i < 4; ++i) {
            int row = d4 + i;
            int slot = lp ^ (((row >> 3) & 3) << 2);
            sB[row * 20 + slot] = (unsigned)f2bf(a0[i]) | ((unsigned)f2bf(a1[i]) << 16);
        }
        __syncthreads();

        short8 a[2], b2[2];
        const int s = lane >> 4;
#pragma unroll
        for (int i = 0; i < 2; ++i) {
            int r = wm * 32 + i * 16 + (lane & 15);
            a[i] = *reinterpret_cast<const short8*>(&sA[r * 32 + (s ^ ((r >> 1) & 3)) * 8]);
        }
#pragma unroll
        for (int j = 0; j < 2; ++j) {
            int d = wn * 32 + j * 16 + (lane & 15);
            int off = d * 20 + ((s * 4) ^ (((d >> 3) & 3) << 2));
            b2[j] = *reinterpret_cast<const short8*>(&sB[off]);
        }
#pragma unroll
        for (int i = 0; i < 2; ++i)
#pragma unroll
            for (int j = 0; j < 2; ++j)
                acc[i][j] = __builtin_amdgcn_mfma_f32_16x16x32_bf16(a[i], b2[j], acc[i][j], 0, 0, 0);
        __syncthreads();
    }

    const int cr = (lane >> 4) * 4, cc = lane & 15;
#pragma unroll
    for (int i = 0; i < 2; ++i)
#pragma unroll
        for (int j = 0; j < 2; ++j)
#pragma unroll
            for (int r = 0; r < 4; ++r) {
                int m = m0 + wm * 32 + i * 16 + cr + r;
                int n = n0 + wn * 32 + j * 16 + cc;
                P[((size_t)z * 128 + m) * 512 + n] = acc[i][j][r];
            }
}

// sum 4 K-slices -> xf bf16
__global__ __launch_bounds__(256)
void dft_reduce(const float* __restrict__ P, unsigned short* __restrict__ Oh)
{
    int i = blockIdx.x * 256 + threadIdx.x;     // 16*128*128 float4s
    int b = i >> 14;
    int r = i & 16383;
    const float4* p = reinterpret_cast<const float4*>(P) + ((size_t)b * 4) * 16384 + r;
    float4 v = p[0];
    float4 v1 = p[16384], v2 = p[2 * 16384], v3 = p[3 * 16384];
    v.x += v1.x + v2.x + v3.x;
    v.y += v1.y + v2.y + v3.y;
    v.z += v1.z + v2.z + v3.z;
    v.w += v1.w + v2.w + v3.w;
    ushort4 h;
    h.x = f2bf(v.x); h.y = f2bf(v.y); h.z = f2bf(v.z); h.w = f2bf(v.w);
    reinterpret_cast<ushort4*>(Oh)[(size_t)b * 16384 + r] = h;
}

// fp32 -> bf16, float4 path
__global__ __launch_bounds__(256)
void cvt_bf16_kernel(const float* __restrict__ src, unsigned short* __restrict__ hi, int n4)
{
    int i = blockIdx.x * 256 + threadIdx.x;
    if (i >= n4) return;
    float4 v = reinterpret_cast<const float4*>(src)[i];
    ushort4 h;
    h.x = f2bf(v.x); h.y = f2bf(v.y); h.z = f2bf(v.z); h.w = f2bf(v.w);
    reinterpret_cast<ushort4*>(hi)[i] = h;
}

// Tables: ft[t][l] (t<64 cos, t>=64 -sin of selected modes), it[l][t], bf16
__global__ void build_tables_kernel(const int* __restrict__ midx,
                                    unsigned short* __restrict__ fth,
                                    unsigned short* __restrict__ ith)
{
    const int l = blockIdx.x;
    const int t = threadIdx.x;
    const int m = t & 63;
    const bool im = t >= 64;
    const float c0 = 6.28318530717958647692f / 2048.0f;

    int f = midx[m];
    int ph = (f * l) & 2047;
    float s, c;
    sincosf(c0 * (float)ph, &s, &c);
    fth[(size_t)t * 2048 + l] = f2bf(im ? -s : c);

    int ph2 = (m * l) & 2047;
    float s2, c2;
    sincosf(c0 * (float)ph2, &s2, &c2);
    ith[(size_t)l * 128 + t] = f2bf(im ? s2 : c2);
}

// Per (m,h): complex channel mix; writes scaled inverse coefficients, bf16.
__global__ __launch_bounds__(256)
void mode_mix_kernel(const float* __restrict__ xsel,
                     const float* __restrict__ wr, const float* __restrict__ wi,
                     unsigned short* __restrict__ cth)
{
    const int m = blockIdx.x;
    const int h = blockIdx.y;
    const int tid = threadIdx.x;

    __shared__ float xr[16][64], xi[16][64];
    __shared__ float wrs[64][65], wis[64][65];

    for (int i = tid; i < 4096; i += 256) {
        int e = i >> 6, o = i & 63;
        size_t g = (((size_t)h * 64 + e) * 64 + o) * 64 + m;
        wrs[e][o] = wr[g];
        wis[e][o] = wi[g];
    }
    for (int i = tid; i < 1024; i += 256) {
        int bb = i >> 6, e = i & 63;
        size_t g = ((size_t)bb * 512 + h * 64 + e) * 128;
        xr[bb][e] = xsel[g + m];
        xi[bb][e] = xsel[g + 64 + m];
    }
    __syncthreads();

    const int o = tid & 63;
    const int bq4 = tid >> 6;
    const float sc_r = (m == 0) ? (1.0f / 2048.0f) : (2.0f / 2048.0f);
    const float sc_i = (m == 0) ? 0.0f : (-2.0f / 2048.0f);

    for (int q = 0; q < 4; ++q) {
        int bb = bq4 * 4 + q;
        float or_ = 0.f, oi_ = 0.f;
#pragma unroll 16
        for (int e = 0; e < 64; ++e) {
            float xrv = xr[bb][e], xiv = xi[bb][e];
            float wrv = wrs[e][o], wiv = wis[e][o];
            or_ += xrv * wrv - xiv * wiv;
            oi_ += xrv * wiv + xiv * wrv;
        }
        size_t base = ((size_t)bb * 128 + m) * 512 + (size_t)h * 64 + o;
        cth[base] = f2bf(or_ * sc_r);
        cth[base + 64 * 512] = f2bf(oi_ * sc_i);
    }
}

// decomp: R = X - sum_k softmax_k(X*w_k+b_k)*movavg_k(X). SPLIT: write hi/lo planes.
template<bool SPLIT>
__global__ __launch_bounds__(256)
void decomp_kernel(const float* __restrict__ X, float* __restrict__ Rf,
                   unsigned short* __restrict__ Rh, unsigned short* __restrict__ Rl,
                   const float* __restrict__ w, const float* __restrict__ bg)
{
    const int d = blockIdx.x * 256 + threadIdx.x;
    const int l0 = blockIdx.y * 32;
    const int b = blockIdx.z;
    const float w0 = w[0], w1 = w[1], b0 = bg[0], b1 = bg[1];

    const float* Xp = X + (size_t)b * 2048 * 512 + d;
    const size_t obase = (size_t)b * 2048 * 512 + d;

    float s1 = 0.f, s2 = 0.f;
    for (int i = l0 - 12; i <= l0 + 12; ++i) {
        int ic = min(max(i, 0), 2047);
        float v = Xp[(size_t)ic * 512];
        s2 += v;
        if (i >= l0 - 6 && i <= l0 + 6) s1 += v;
    }
    for (int l = l0; l < l0 + 32; ++l) {
        float xv = Xp[(size_t)l * 512];
        float m1 = s1 * (1.0f / 13.0f);
        float m2 = s2 * (1.0f / 25.0f);
        float e0 = xv * w0 + b0, e1 = xv * w1 + b1;
        float mx = fmaxf(e0, e1);
        float g0 = expf(e0 - mx), g1 = expf(e1 - mx);
        float mean = (g0 * m1 + g1 * m2) / (g0 + g1);
        float rv = xv - mean;
        size_t oi = obase + (size_t)l * 512;
        if (SPLIT) {
            unsigned short h = f2bf(rv);
            Rh[oi] = h;
            Rl[oi] = f2bf(rv - bf2f(h));
        } else {
            Rf[oi] = rv;
        }
        s1 += Xp[(size_t)min(l + 7, 2047) * 512] - Xp[(size_t)max(l - 6, 0) * 512];
        s2 += Xp[(size_t)min(l + 13, 2047) * 512] - Xp[(size_t)max(l - 12, 0) * 512];
    }
}

extern "C" void kernel_launch(void* const* d_in, const int* in_sizes, int n_in,
                              void* d_out, int out_size, void* d_ws, size_t ws_size,
                              hipStream_t stream)
{
    const float* x    = (const float*)d_in[0];
    const float* Wq   = (const float*)d_in[1];
    const float* bq   = (const float*)d_in[2];
    const float* Wo   = (const float*)d_in[7];
    const float* bo   = (const float*)d_in[8];
    const float* fwr  = (const float*)d_in[9];
    const float* fwi  = (const float*)d_in[10];
    const float* c1w  = (const float*)d_in[11];
    const float* c2w  = (const float*)d_in[12];
    const float* d1w  = (const float*)d_in[13];
    const float* d1b  = (const float*)d_in[14];
    const float* d2w  = (const float*)d_in[15];
    const float* d2b  = (const float*)d_in[16];
    const int*   midx = (const int*)d_in[17];
    float* out = (float*)d_out;
    float* ws  = (float*)d_ws;

    // ws layout:
    //  [0   : 64MB)   region0: K1 partials (16MB) -> u -> v
    //  [64MB: 72MB)   phase-1 bf16 planes (dead after K5); FFN-time: c1h,c2h
    //  [72MB: 76MB)   xsel fp32 (dead after K3)
    //  [72MB: 104MB)  h bf16 plane at FFN time (R=8192)
    float* region0 = ws;
    unsigned short* p1 = (unsigned short*)(ws + 16777216);   // 64MB
    unsigned short* fth = p1;                    // 128x2048
    unsigned short* ith = p1 + 262144;           // 2048x128
    unsigned short* wqh = p1 + 2 * 262144;       // 512x512
    unsigned short* woh = p1 + 3 * 262144;
    unsigned short* xfh = p1 + 1048576;          // 16x128x512
    unsigned short* cth = p1 + 2097152;
    unsigned short* zth = p1 + 3145728;
    float* xsel = (float*)(p1 + 4194304);        // 72MB..76MB fp32

    // FFN-time (phase-1 planes dead):
    unsigned short* c1h = p1;                    // 2048x512
    unsigned short* c2h = p1 + 1048576;          // 512x2048
    unsigned short* hh  = (unsigned short*)(ws + 18874368);  // 72MB
    const size_t hbase = 72ull << 20;
    const int R = (ws_size >= hbase + (size_t)8192 * 2048 * 2) ? 8192 : 4096;

    // r1 hi/lo planes live in d_out until K8 (d_out fully rewritten by K8)
    unsigned short* r1h = (unsigned short*)d_out;
    unsigned short* r1l = r1h + 16777216;

    const long long sBL = (long long)2048 * 512;
    const long long sP  = 65536;

    // T: tables + weight casts
    build_tables_kernel<<<2048, 128, 0, stream>>>(midx, fth, ith);
    cvt_bf16_kernel<<<256, 256, 0, stream>>>(Wq, wqh, 65536);
    cvt_bf16_kernel<<<256, 256, 0, stream>>>(Wo, woh, 65536);

    // K1: split-K x4 partials into region0, then reduce -> xf bf16
    gemm_dft<<<dim3(8, 2, 64), 256, 0, stream>>>(fth, x, sBL, region0);
    dft_reduce<<<1024, 256, 0, stream>>>(region0, xfh);

    // K2: xsel = Wq @ xf^T (+ bq*L on f==0 real modes)
    gemm_hl<64, 64, EPI_WQFOLD><<<dim3(2, 8, 16), 512, 0, stream>>>(
        wqh, 0, xfh, sP, xsel, nullptr, sP,
        nullptr, nullptr, nullptr, 0, bq, midx, 128, 512);

    // K3: mode mixing -> coef bf16
    mode_mix_kernel<<<dim3(64, 8), 256, 0, stream>>>(xsel, fwr, fwi, cth);

    // K4: zc = Wo @ coef^T -> bf16
    gemm_hl<64, 64, EPI_BF16><<<dim3(2, 8, 16), 512, 0, stream>>>(
        woh, 0, cth, sP, nullptr, zth, sP,
        nullptr, nullptr, nullptr, 0, nullptr, nullptr, 128, 512);

    // K5: u = x + bo + it @ zc^T
    gemm_hl<128, 128, EPI_INVU><<<dim3(4, 16, 16), 512, 0, stream>>>(
        ith, 0, zth, sP, region0, nullptr, sBL,
        nullptr, nullptr, x, sBL, bo, nullptr, 512, 128);

    // K6: r1 = decomp(u) -> hi/lo planes in d_out
    decomp_kernel<true><<<dim3(2, 64, 16), 256, 0, stream>>>(
        region0, nullptr, r1h, r1l, d1w, d1b);

    // FFN weight casts (phase-1 planes now dead)
    cvt_bf16_kernel<<<1024, 256, 0, stream>>>(c1w, c1h, 262144);
    cvt_bf16_kernel<<<1024, 256, 0, stream>>>(c2w, c2h, 262144);

    // FFN chunks; u dead -> region0 receives v
    const int nc = 32768 / R;
    for (int c = 0; c < nc; ++c) {
        const unsigned short* r1hc = r1h + (size_t)c * R * 512;
        const unsigned short* r1lc = r1l + (size_t)c * R * 512;
        gemm_hl<128, 128, EPI_GELU><<<dim3(16, R / 128), 512, 0, stream>>>(
            r1hc, 0, c1h, 0, nullptr, hh, 0,
            nullptr, nullptr, nullptr, 0, nullptr, nullptr, 2048, 512);
        gemm_hl<128, 128, EPI_RES><<<dim3(4, R / 128), 512, 0, stream>>>(
            hh, 0, c2h, 0, region0 + (size_t)c * R * 512, nullptr, 0,
            r1hc, r1lc, nullptr, 0, nullptr, nullptr, 512, 2048);
    }

    // K8: out = decomp(v)
    decomp_kernel<false><<<dim3(2, 64, 16), 256, 0, stream>>>(
        region0, out, nullptr, nullptr, d2w, d2b);
}